// Round 4
// baseline (384.329 us; speedup 1.0000x reference)
//
#include <hip/hip_runtime.h>

// B=2, S=2048, D=1024, H=16, DK=64.  I/O fp32; internal MFMA pipeline bf16.
typedef __bf16 bf16x8 __attribute__((ext_vector_type(8)));
typedef float  f32x4  __attribute__((ext_vector_type(4)));
typedef float  f32x16 __attribute__((ext_vector_type(16)));

#define AS1 __attribute__((address_space(1)))
#define AS3 __attribute__((address_space(3)))

__device__ __forceinline__ void g2l16(const void* g, void* l) {
  __builtin_amdgcn_global_load_lds((AS1 void*)g, (AS3 void*)l, 16, 0, 0);
}
#define MFMA16(a, b, c) __builtin_amdgcn_mfma_f32_16x16x32_bf16(a, b, c, 0, 0, 0)
#define MFMA32(a, b, c) __builtin_amdgcn_mfma_f32_32x32x16_bf16(a, b, c, 0, 0, 0)

__device__ __forceinline__ unsigned pack_bf16(float a, float b) {
  union { __bf16 h[2]; unsigned u; } p;
  p.h[0] = (__bf16)a; p.h[1] = (__bf16)b;
  return p.u;
}

// ---------------- fp32 -> bf16 cast of the three activation tensors ----------------
__global__ __launch_bounds__(256) void cvt_bf16_3(const float* __restrict__ a,
    const float* __restrict__ b, const float* __restrict__ c,
    __bf16* __restrict__ oa, __bf16* __restrict__ ob, __bf16* __restrict__ oc) {
  const float* src = blockIdx.y == 0 ? a : (blockIdx.y == 1 ? b : c);
  __bf16* dst = blockIdx.y == 0 ? oa : (blockIdx.y == 1 ? ob : oc);
  size_t base = ((size_t)blockIdx.x * 256 + threadIdx.x) * 8;
  float4 f0 = *(const float4*)(src + base);
  float4 f1 = *(const float4*)(src + base + 4);
  bf16x8 o;
  o[0] = (__bf16)f0.x; o[1] = (__bf16)f0.y; o[2] = (__bf16)f0.z; o[3] = (__bf16)f0.w;
  o[4] = (__bf16)f1.x; o[5] = (__bf16)f1.y; o[6] = (__bf16)f1.z; o[7] = (__bf16)f1.w;
  *(bf16x8*)(dst + base) = o;
}

// ---------------- mask -> bitmask ----------------
__global__ __launch_bounds__(256) void mask_pack(const int* __restrict__ mask,
                                                 unsigned long long* __restrict__ bits) {
  int i = blockIdx.x * 256 + threadIdx.x;
  unsigned long long b = __ballot(mask[i] != 0);
  if ((threadIdx.x & 63) == 0) bits[i >> 6] = b;
}

// ---------------- transpose + cast weights (fp32 -> bf16^T) ----------------
__global__ __launch_bounds__(256) void transpose_w4(const float* __restrict__ w0,
    const float* __restrict__ w1, const float* __restrict__ w2,
    const float* __restrict__ w3, __bf16* __restrict__ out) {
  __shared__ __bf16 tile[64][65];
  const float* srcs[4] = {w0, w1, w2, w3};
  const float* src = srcs[blockIdx.z];
  __bf16* dst = out + (size_t)blockIdx.z * 1024 * 1024;
  int cb = blockIdx.x * 64, rb = blockIdx.y * 64;
  for (int i = threadIdx.x; i < 4096; i += 256) {
    int r = i >> 6, c = i & 63;
    tile[r][c] = (__bf16)src[(size_t)(rb + r) * 1024 + cb + c];
  }
  __syncthreads();
  for (int i = threadIdx.x; i < 4096; i += 256) {
    int c = i >> 6, r = i & 63;
    dst[(size_t)(cb + c) * 1024 + rb + r] = tile[r][c];
  }
}

// ---------------- transpose V: [BH][S][DK] -> [BH][DK][S] ----------------
__global__ __launch_bounds__(256) void transpose_v(const __bf16* __restrict__ src,
                                                   __bf16* __restrict__ dst) {
  __shared__ __bf16 tile[64][65];
  int rb = blockIdx.y * 64;
  size_t zo = (size_t)blockIdx.z * 2048 * 64;
  for (int i = threadIdx.x; i < 4096; i += 256) {
    int r = i >> 6, c = i & 63;
    tile[r][c] = src[zo + (size_t)(rb + r) * 64 + c];
  }
  __syncthreads();
  for (int i = threadIdx.x; i < 4096; i += 256) {
    int c = i >> 6, r = i & 63;
    dst[zo + (size_t)c * 2048 + rb + r] = tile[r][c];
  }
}

// ---------------- QKV projection GEMM, 128x128 tile, BK=32, single-barrier dbuf ----------------
__global__ __launch_bounds__(256) void qkv_gemm(const __bf16* __restrict__ Xq,
    const __bf16* __restrict__ Xk, const __bf16* __restrict__ Xv,
    const __bf16* __restrict__ Wt, __bf16* __restrict__ Qb,
    __bf16* __restrict__ Kb, __bf16* __restrict__ Vb) {
  __shared__ __align__(16) __bf16 As[2][128 * 32];
  __shared__ __align__(16) __bf16 Bs[2][128 * 32];
  const int z = blockIdx.z;
  const __bf16* X = z == 0 ? Xq : (z == 1 ? Xk : Xv);
  const __bf16* W = Wt + (size_t)z * 1048576;
  __bf16* Y = z == 0 ? Qb : (z == 1 ? Kb : Vb);
  const float scale = z == 0 ? 0.125f * 1.44269504088896f : 1.f;  // log2e/sqrt(DK) into Q
  const int t = threadIdx.x;
  const int lane = t & 63, w = t >> 6;
  const int lane15 = lane & 15, quad = lane >> 4;
  const int wm = (w >> 1) * 64, wn = (w & 1) * 64;
  const int mBase = blockIdx.y * 128, nBase = blockIdx.x * 128;
  const int c1 = t, c2 = t + 256;
  f32x4 acc[4][4] = {};
  // stage tile 0
  g2l16(X + (size_t)(mBase + (c1 >> 2)) * 1024 + (c1 & 3) * 8, &As[0][0] + c1 * 8);
  g2l16(X + (size_t)(mBase + (c2 >> 2)) * 1024 + (c2 & 3) * 8, &As[0][0] + c2 * 8);
  g2l16(W + (size_t)(nBase + (c1 >> 2)) * 1024 + (c1 & 3) * 8, &Bs[0][0] + c1 * 8);
  g2l16(W + (size_t)(nBase + (c2 >> 2)) * 1024 + (c2 & 3) * 8, &Bs[0][0] + c2 * 8);
  int cur = 0;
  for (int kt = 0; kt < 32; ++kt) {
    __syncthreads();   // auto vmcnt(0) drain covers stage of tile kt, issued one iter ago
    if (kt < 31) {
      const int ko = (kt + 1) * 32;
      g2l16(X + (size_t)(mBase + (c1 >> 2)) * 1024 + ko + (c1 & 3) * 8, &As[cur ^ 1][0] + c1 * 8);
      g2l16(X + (size_t)(mBase + (c2 >> 2)) * 1024 + ko + (c2 & 3) * 8, &As[cur ^ 1][0] + c2 * 8);
      g2l16(W + (size_t)(nBase + (c1 >> 2)) * 1024 + ko + (c1 & 3) * 8, &Bs[cur ^ 1][0] + c1 * 8);
      g2l16(W + (size_t)(nBase + (c2 >> 2)) * 1024 + ko + (c2 & 3) * 8, &Bs[cur ^ 1][0] + c2 * 8);
    }
    bf16x8 a[4], b[4];
#pragma unroll
    for (int i = 0; i < 4; i++) a[i] = *(const bf16x8*)&As[cur][(wm + i * 16 + lane15) * 32 + quad * 8];
#pragma unroll
    for (int j = 0; j < 4; j++) b[j] = *(const bf16x8*)&Bs[cur][(wn + j * 16 + lane15) * 32 + quad * 8];
#pragma unroll
    for (int i = 0; i < 4; i++)
#pragma unroll
      for (int j = 0; j < 4; j++)
        acc[i][j] = MFMA16(a[i], b[j], acc[i][j]);
    cur ^= 1;
  }
#pragma unroll
  for (int i = 0; i < 4; i++)
#pragma unroll
    for (int j = 0; j < 4; j++)
#pragma unroll
      for (int r = 0; r < 4; r++) {
        int mg = mBase + wm + i * 16 + quad * 4 + r;
        int ng = nBase + wn + j * 16 + lane15;
        int b_ = mg >> 11, s_ = mg & 2047, h_ = ng >> 6, d_ = ng & 63;
        Y[(((size_t)(b_ * 16 + h_)) * 2048 + s_) * 64 + d_] = (__bf16)(acc[i][j][r] * scale);
      }
}

// ---------------- output projection + fp32 residual, same dbuf structure ----------------
__global__ __launch_bounds__(256) void gemm_wo(const __bf16* __restrict__ X,
    const __bf16* __restrict__ Wt, const float* __restrict__ resid,
    float* __restrict__ Yf) {
  __shared__ __align__(16) __bf16 As[2][128 * 32];
  __shared__ __align__(16) __bf16 Bs[2][128 * 32];
  const int t = threadIdx.x;
  const int lane = t & 63, w = t >> 6;
  const int lane15 = lane & 15, quad = lane >> 4;
  const int wm = (w >> 1) * 64, wn = (w & 1) * 64;
  const int mBase = blockIdx.y * 128, nBase = blockIdx.x * 128;
  const int c1 = t, c2 = t + 256;
  f32x4 acc[4][4] = {};
  g2l16(X  + (size_t)(mBase + (c1 >> 2)) * 1024 + (c1 & 3) * 8, &As[0][0] + c1 * 8);
  g2l16(X  + (size_t)(mBase + (c2 >> 2)) * 1024 + (c2 & 3) * 8, &As[0][0] + c2 * 8);
  g2l16(Wt + (size_t)(nBase + (c1 >> 2)) * 1024 + (c1 & 3) * 8, &Bs[0][0] + c1 * 8);
  g2l16(Wt + (size_t)(nBase + (c2 >> 2)) * 1024 + (c2 & 3) * 8, &Bs[0][0] + c2 * 8);
  int cur = 0;
  for (int kt = 0; kt < 32; ++kt) {
    __syncthreads();
    if (kt < 31) {
      const int ko = (kt + 1) * 32;
      g2l16(X  + (size_t)(mBase + (c1 >> 2)) * 1024 + ko + (c1 & 3) * 8, &As[cur ^ 1][0] + c1 * 8);
      g2l16(X  + (size_t)(mBase + (c2 >> 2)) * 1024 + ko + (c2 & 3) * 8, &As[cur ^ 1][0] + c2 * 8);
      g2l16(Wt + (size_t)(nBase + (c1 >> 2)) * 1024 + ko + (c1 & 3) * 8, &Bs[cur ^ 1][0] + c1 * 8);
      g2l16(Wt + (size_t)(nBase + (c2 >> 2)) * 1024 + ko + (c2 & 3) * 8, &Bs[cur ^ 1][0] + c2 * 8);
    }
    bf16x8 a[4], b[4];
#pragma unroll
    for (int i = 0; i < 4; i++) a[i] = *(const bf16x8*)&As[cur][(wm + i * 16 + lane15) * 32 + quad * 8];
#pragma unroll
    for (int j = 0; j < 4; j++) b[j] = *(const bf16x8*)&Bs[cur][(wn + j * 16 + lane15) * 32 + quad * 8];
#pragma unroll
    for (int i = 0; i < 4; i++)
#pragma unroll
      for (int j = 0; j < 4; j++)
        acc[i][j] = MFMA16(a[i], b[j], acc[i][j]);
    cur ^= 1;
  }
#pragma unroll
  for (int i = 0; i < 4; i++)
#pragma unroll
    for (int j = 0; j < 4; j++)
#pragma unroll
      for (int r = 0; r < 4; r++) {
        int mg = mBase + wm + i * 16 + quad * 4 + r;
        int ng = nBase + wn + j * 16 + lane15;
        size_t idx = (size_t)mg * 1024 + ng;
        Yf[idx] = acc[i][j][r] + resid[idx];
      }
}

// ---------------- flash attention, 32x32x16 MFMA, single-barrier dbuf K/V ----------------
// Block: 4 waves, 128 q-rows (wave w owns q [w*32, w*32+32)); t-tiles of 64.
// S^T = K·Q^T so C-layout has q on lanes (col=lane&31), t on regs -> one mask word
// per lane, reg-pairs = consecutive t -> packed b32 P-writes.
// LDS xor swizzle: element (row,e) at row*64 + ((e/8 ^ (row&7))*8) + e%8.
__global__ __launch_bounds__(256) void attn_kernel(const __bf16* __restrict__ Q,
    const __bf16* __restrict__ Kp, const __bf16* __restrict__ Vt,
    const unsigned long long* __restrict__ mbits, __bf16* __restrict__ ctx) {
  __shared__ __align__(16) __bf16 Ks[2][64 * 64];
  __shared__ __align__(16) __bf16 Vs[2][64 * 64];
  __shared__ __align__(16) __bf16 Ps[4][32 * 64];   // per-wave P; also Q staging (row-major 128x64)
  const int t = threadIdx.x, lane = t & 63, w = t >> 6;
  const int l31 = lane & 31, hi = lane >> 5;        // hi in {0,1}
  const int bh = blockIdx.y, b = bh >> 4, h = bh & 15;
  const int qBase = blockIdx.x * 128;
  const size_t qko = (size_t)bh * 2048 * 64;
  const size_t vko = (size_t)bh * 64 * 2048;
  const int srow = lane >> 3, schunk = (lane & 7) ^ srow;   // staging map per 8-row group
  __bf16* PsAll = &Ps[0][0];
  // stage Q (128 rows = 16 groups; thread's wave handles n = w,w+4,w+8,w+12)
#pragma unroll
  for (int n = w; n < 16; n += 4)
    g2l16(Q + qko + (size_t)(qBase + n * 8 + srow) * 64 + schunk * 8, PsAll + n * 512 + lane * 8);
  // stage K/V tile 0
  g2l16(Kp + qko + (size_t)(w * 8 + srow) * 64 + schunk * 8,        &Ks[0][0] + w * 512 + lane * 8);
  g2l16(Kp + qko + (size_t)((w + 4) * 8 + srow) * 64 + schunk * 8,  &Ks[0][0] + (w + 4) * 512 + lane * 8);
  g2l16(Vt + vko + (size_t)(w * 8 + srow) * 2048 + schunk * 8,       &Vs[0][0] + w * 512 + lane * 8);
  g2l16(Vt + vko + (size_t)((w + 4) * 8 + srow) * 2048 + schunk * 8, &Vs[0][0] + (w + 4) * 512 + lane * 8);
  __builtin_amdgcn_s_waitcnt(0);
  __syncthreads();
  // extract Q fragments (wave-private region rows w*32..): B-frag [n=q=l31][k]
  bf16x8 qa[4];
  {
    const int r = w * 32 + l31;
#pragma unroll
    for (int s = 0; s < 4; s++) {
      const int c = s * 2 + hi;
      qa[s] = *(const bf16x8*)&PsAll[r * 64 + ((c ^ (r & 7)) * 8)];
    }
  }
  bf16x8 ones;
#pragma unroll
  for (int i = 0; i < 8; i++) ones[i] = (__bf16)1.0f;
  f32x16 o[2] = {};   // o[dtile]: D[m=q][n=d]
  f32x16 ol = {};     // row sums (B=ones)
  const size_t mrow = ((size_t)b * 2048 + qBase + w * 32 + l31) * 32;
  int cur = 0;
  for (int kt = 0; kt < 32; ++kt) {
    __syncthreads();   // auto vmcnt(0)+lgkm(0) drain: tile-kt staging (issued last iter) complete
    unsigned long long w64 = mbits[mrow + kt];
    if (kt < 31) {     // stage tile kt+1 into the buffer everyone just finished reading
      const int nb = cur ^ 1, tB = (kt + 1) * 64;
      g2l16(Kp + qko + (size_t)(tB + w * 8 + srow) * 64 + schunk * 8,        &Ks[nb][0] + w * 512 + lane * 8);
      g2l16(Kp + qko + (size_t)(tB + (w + 4) * 8 + srow) * 64 + schunk * 8,  &Ks[nb][0] + (w + 4) * 512 + lane * 8);
      g2l16(Vt + vko + (size_t)(w * 8 + srow) * 2048 + tB + schunk * 8,       &Vs[nb][0] + w * 512 + lane * 8);
      g2l16(Vt + vko + (size_t)((w + 4) * 8 + srow) * 2048 + tB + schunk * 8, &Vs[nb][0] + (w + 4) * 512 + lane * 8);
    }
    // S^T = K·Q^T : A=K rows t, B=qa; 2 m-tiles (t 0-31, 32-63) x 4 k-steps
    f32x16 st[2] = {};
#pragma unroll
    for (int m = 0; m < 2; m++) {
      const int tl = m * 32 + l31;
      const int swk = (tl & 7);
#pragma unroll
      for (int s = 0; s < 4; s++) {
        const int c = s * 2 + hi;
        bf16x8 ka = *(const bf16x8*)&Ks[cur][tl * 64 + ((c ^ swk) * 8)];
        st[m] = MFMA32(ka, qa[s], st[m]);
      }
    }
    // mask + exp2 + packed P write: P^T element (t, q=l31) -> Ps[w][q][t] swizzled
#pragma unroll
    for (int m = 0; m < 2; m++)
#pragma unroll
      for (int rp = 0; rp < 8; rp++) {
        const int r0 = rp * 2;
        const int tr = (r0 & 3) + 8 * (r0 >> 2) + 4 * hi + m * 32;
        float e0 = ((w64 >> tr) & 1ull) ? 0.f : __builtin_exp2f(st[m][r0]);
        float e1 = ((w64 >> (tr + 1)) & 1ull) ? 0.f : __builtin_exp2f(st[m][r0 + 1]);
        const int chunk = (r0 >> 2) + m * 4;            // t/8 (uniform per reg-pair)
        const int sw = chunk ^ (l31 & 7);
        *(unsigned*)((char*)&Ps[w][0] + l31 * 128 + sw * 16 + (tr & 7) * 2) = pack_bf16(e0, e1);
      }
    __builtin_amdgcn_s_waitcnt(0xC07F);   // lgkmcnt(0): own-wave P writes visible
    // P fragments: A[m=q=l31][k=t]
    bf16x8 pa[4];
#pragma unroll
    for (int s = 0; s < 4; s++) {
      const int c = s * 2 + hi;
      pa[s] = *(const bf16x8*)&Ps[w][l31 * 64 + ((c ^ (l31 & 7)) * 8)];
    }
#pragma unroll
    for (int s = 0; s < 4; s++) ol = MFMA32(pa[s], ones, ol);
    // o[q][d] += P·V : B = V[n=d][k=t] from Vs[d][t]
#pragma unroll
    for (int dt = 0; dt < 2; dt++) {
      const int dr = dt * 32 + l31;
      const int swk = (dr & 7);
#pragma unroll
      for (int s = 0; s < 4; s++) {
        const int c = s * 2 + hi;
        bf16x8 vb = *(const bf16x8*)&Vs[cur][dr * 64 + ((c ^ swk) * 8)];
        o[dt] = MFMA32(pa[s], vb, o[dt]);
      }
    }
    cur ^= 1;
  }
  // epilogue: ctx[b][q][h*64 + dt*32 + l31] = o/ol
#pragma unroll
  for (int r = 0; r < 16; r++) {
    const int qrow = (r & 3) + 8 * (r >> 2) + 4 * hi;
    const float inv = 1.f / ol[r];
    const size_t base = ((size_t)b * 2048 + qBase + w * 32 + qrow) * 1024 + h * 64;
    ctx[base + l31]      = (__bf16)(o[0][r] * inv);
    ctx[base + 32 + l31] = (__bf16)(o[1][r] * inv);
  }
}

// ---------------- LayerNorm over D=1024 per row (fp32) ----------------
__global__ __launch_bounds__(256) void ln_kernel(const float* __restrict__ X,
    const float* __restrict__ gamma, const float* __restrict__ beta,
    float* __restrict__ out) {
  __shared__ float red[8];
  const int t = threadIdx.x;
  const size_t row = blockIdx.x;
  const float* xr = X + row * 1024;
  float4 x = *(const float4*)(xr + t * 4);
  float s = x.x + x.y + x.z + x.w;
  float s2 = x.x * x.x + x.y * x.y + x.z * x.z + x.w * x.w;
#pragma unroll
  for (int off = 1; off < 64; off <<= 1) { s += __shfl_xor(s, off); s2 += __shfl_xor(s2, off); }
  if ((t & 63) == 0) { red[t >> 6] = s; red[4 + (t >> 6)] = s2; }
  __syncthreads();
  float S1 = red[0] + red[1] + red[2] + red[3];
  float S2 = red[4] + red[5] + red[6] + red[7];
  float mu = S1 * (1.f / 1024.f);
  float var = S2 * (1.f / 1024.f) - mu * mu;
  float rs = rsqrtf(var + 1e-5f);
  float4 g = *(const float4*)(gamma + t * 4);
  float4 bb = *(const float4*)(beta + t * 4);
  float4 y;
  y.x = (x.x - mu) * rs * g.x + bb.x;
  y.y = (x.y - mu) * rs * g.y + bb.y;
  y.z = (x.z - mu) * rs * g.z + bb.z;
  y.w = (x.w - mu) * rs * g.w + bb.w;
  *(float4*)(out + row * 1024 + t * 4) = y;
}

extern "C" void kernel_launch(void* const* d_in, const int* in_sizes, int n_in,
                              void* d_out, int out_size, void* d_ws, size_t ws_size,
                              hipStream_t stream) {
  const float* inQ  = (const float*)d_in[0];
  const float* inK  = (const float*)d_in[1];
  const float* inV  = (const float*)d_in[2];
  const int*   mask = (const int*)d_in[3];
  const float* WQ   = (const float*)d_in[4];
  const float* WK   = (const float*)d_in[5];
  const float* WV   = (const float*)d_in[6];
  const float* WO   = (const float*)d_in[7];
  const float* gamma = (const float*)d_in[8];
  const float* beta  = (const float*)d_in[9];

  const size_t MB = 1024 * 1024;
  char* ws = (char*)d_ws;
  __bf16* Xq  = (__bf16*)(ws);                    // 8 MB each
  __bf16* Xk  = (__bf16*)(ws + 8 * MB);
  __bf16* Xv  = (__bf16*)(ws + 16 * MB);
  __bf16* Qb  = (__bf16*)(ws + 24 * MB);          // [BH][S][DK]
  __bf16* Kb  = (__bf16*)(ws + 32 * MB);
  __bf16* Vb  = (__bf16*)(ws + 40 * MB);
  __bf16* Vtb = (__bf16*)(ws + 48 * MB);          // [BH][DK][S]
  __bf16* Wt  = (__bf16*)(ws + 56 * MB);          // 4x 2MB bf16^T weights
  unsigned long long* mbits = (unsigned long long*)(ws + 64 * MB);
  __bf16* ctx  = Xq;                              // reuse
  float*  outp = (float*)(ws + 8 * MB);           // reuse Xk+Xv

  cvt_bf16_3<<<dim3(2048, 3), 256, 0, stream>>>(inQ, inK, inV, Xq, Xk, Xv);
  mask_pack<<<dim3(2 * 2048 * 2048 / 256), 256, 0, stream>>>(mask, mbits);
  transpose_w4<<<dim3(16, 16, 4), 256, 0, stream>>>(WQ, WK, WV, WO, Wt);

  qkv_gemm<<<dim3(8, 32, 3), 256, 0, stream>>>(Xq, Xk, Xv, Wt, Qb, Kb, Vb);

  transpose_v<<<dim3(1, 32, 32), 256, 0, stream>>>(Vb, Vtb);
  attn_kernel<<<dim3(16, 32), 256, 0, stream>>>(Qb, Kb, Vtb, mbits, ctx);

  gemm_wo<<<dim3(8, 32), 256, 0, stream>>>(ctx, Wt + 3 * 1048576, inQ, outp);
  ln_kernel<<<dim3(4096), 256, 0, stream>>>(outp, gamma, beta, (float*)d_out);
}

// Round 5
// 322.453 us; speedup vs baseline: 1.1919x; 1.1919x over previous
//
#include <hip/hip_runtime.h>

// B=2, S=2048, D=1024, H=16, DK=64.  I/O fp32; internal MFMA pipeline bf16.
typedef __bf16 bf16x8 __attribute__((ext_vector_type(8)));
typedef float  f32x4  __attribute__((ext_vector_type(4)));

#define AS1 __attribute__((address_space(1)))
#define AS3 __attribute__((address_space(3)))

__device__ __forceinline__ void g2l16(const void* g, void* l) {
  __builtin_amdgcn_global_load_lds((AS1 void*)g, (AS3 void*)l, 16, 0, 0);
}
#define MFMA16(a, b, c) __builtin_amdgcn_mfma_f32_16x16x32_bf16(a, b, c, 0, 0, 0)

__device__ __forceinline__ unsigned pack_bf16(float a, float b) {
  union { __bf16 h[2]; unsigned u; } p;
  p.h[0] = (__bf16)a; p.h[1] = (__bf16)b;
  return p.u;
}

// ---------------- fused prep: cvt x3 | mask_pack | transpose_w4, one launch ----------------
// blocks [0,6144): fp32->bf16 cast of inQ/inK/inV (2048 blocks each)
// blocks [6144,10240): mask -> bitmask (2048 elems/block)
// blocks [10240,11264): weight transpose+cast (4 x 256 tile-blocks)
__global__ __launch_bounds__(256) void prep(const float* __restrict__ inQ,
    const float* __restrict__ inK, const float* __restrict__ inV,
    const int* __restrict__ mask,
    const float* __restrict__ W0, const float* __restrict__ W1,
    const float* __restrict__ W2, const float* __restrict__ W3,
    __bf16* __restrict__ Xq, __bf16* __restrict__ Xk, __bf16* __restrict__ Xv,
    unsigned long long* __restrict__ bits, __bf16* __restrict__ Wt) {
  __shared__ __bf16 tile[64][65];
  const int blk = blockIdx.x;
  if (blk < 6144) {
    const int z = blk >> 11, bx = blk & 2047;
    const float* src = z == 0 ? inQ : (z == 1 ? inK : inV);
    __bf16* dst = z == 0 ? Xq : (z == 1 ? Xk : Xv);
    size_t base = ((size_t)bx * 256 + threadIdx.x) * 8;
    float4 f0 = *(const float4*)(src + base);
    float4 f1 = *(const float4*)(src + base + 4);
    bf16x8 o;
    o[0] = (__bf16)f0.x; o[1] = (__bf16)f0.y; o[2] = (__bf16)f0.z; o[3] = (__bf16)f0.w;
    o[4] = (__bf16)f1.x; o[5] = (__bf16)f1.y; o[6] = (__bf16)f1.z; o[7] = (__bf16)f1.w;
    *(bf16x8*)(dst + base) = o;
  } else if (blk < 10240) {
    const int lane = threadIdx.x & 63, w = threadIdx.x >> 6;
    const int base = (blk - 6144) * 2048 + w * 512;
#pragma unroll
    for (int it = 0; it < 8; ++it) {
      int i = base + it * 64 + lane;
      unsigned long long bb = __ballot(mask[i] != 0);
      if (lane == 0) bits[i >> 6] = bb;
    }
  } else {
    const int idx = blk - 10240;
    const int z = idx >> 8, rem = idx & 255, bx = rem & 15, by = rem >> 4;
    const float* srcs[4] = {W0, W1, W2, W3};
    const float* src = srcs[z];
    __bf16* dst = Wt + (size_t)z * 1024 * 1024;
    int cb = bx * 64, rb = by * 64;
    for (int i = threadIdx.x; i < 4096; i += 256) {
      int r = i >> 6, c = i & 63;
      tile[r][c] = (__bf16)src[(size_t)(rb + r) * 1024 + cb + c];
    }
    __syncthreads();
    for (int i = threadIdx.x; i < 4096; i += 256) {
      int c = i >> 6, r = i & 63;
      dst[(size_t)(cb + c) * 1024 + rb + r] = tile[r][c];
    }
  }
}

// ---------------- transpose V: [BH][S][DK] -> [BH][DK][S] ----------------
__global__ __launch_bounds__(256) void transpose_v(const __bf16* __restrict__ src,
                                                   __bf16* __restrict__ dst) {
  __shared__ __bf16 tile[64][65];
  int rb = blockIdx.y * 64;
  size_t zo = (size_t)blockIdx.z * 2048 * 64;
  for (int i = threadIdx.x; i < 4096; i += 256) {
    int r = i >> 6, c = i & 63;
    tile[r][c] = src[zo + (size_t)(rb + r) * 64 + c];
  }
  __syncthreads();
  for (int i = threadIdx.x; i < 4096; i += 256) {
    int c = i >> 6, r = i & 63;
    dst[zo + (size_t)c * 2048 + rb + r] = tile[r][c];
  }
}

// ---------------- QKV projection GEMM, 128x128 tile, BK=32 (R3 2-barrier form) ----------------
__global__ __launch_bounds__(256) void qkv_gemm(const __bf16* __restrict__ Xq,
    const __bf16* __restrict__ Xk, const __bf16* __restrict__ Xv,
    const __bf16* __restrict__ Wt, __bf16* __restrict__ Qb,
    __bf16* __restrict__ Kb, __bf16* __restrict__ Vb) {
  __shared__ __align__(16) __bf16 As[128 * 32];
  __shared__ __align__(16) __bf16 Bs[128 * 32];
  const int z = blockIdx.z;
  const __bf16* X = z == 0 ? Xq : (z == 1 ? Xk : Xv);
  const __bf16* W = Wt + (size_t)z * 1048576;
  __bf16* Y = z == 0 ? Qb : (z == 1 ? Kb : Vb);
  const float scale = z == 0 ? 0.125f * 1.44269504088896f : 1.f;  // log2e/sqrt(DK) into Q
  const int t = threadIdx.x;
  const int lane = t & 63, w = t >> 6;
  const int lane15 = lane & 15, quad = lane >> 4;
  const int wm = (w >> 1) * 64, wn = (w & 1) * 64;
  const int mBase = blockIdx.y * 128, nBase = blockIdx.x * 128;
  const int c1 = t, c2 = t + 256;
  f32x4 acc[4][4] = {};
  for (int kt = 0; kt < 1024; kt += 32) {
    __syncthreads();
    g2l16(X + (size_t)(mBase + (c1 >> 2)) * 1024 + kt + (c1 & 3) * 8, As + c1 * 8);
    g2l16(X + (size_t)(mBase + (c2 >> 2)) * 1024 + kt + (c2 & 3) * 8, As + c2 * 8);
    g2l16(W + (size_t)(nBase + (c1 >> 2)) * 1024 + kt + (c1 & 3) * 8, Bs + c1 * 8);
    g2l16(W + (size_t)(nBase + (c2 >> 2)) * 1024 + kt + (c2 & 3) * 8, Bs + c2 * 8);
    __builtin_amdgcn_s_waitcnt(0);
    __syncthreads();
    bf16x8 a[4], b[4];
#pragma unroll
    for (int i = 0; i < 4; i++) a[i] = *(const bf16x8*)&As[(wm + i * 16 + lane15) * 32 + quad * 8];
#pragma unroll
    for (int j = 0; j < 4; j++) b[j] = *(const bf16x8*)&Bs[(wn + j * 16 + lane15) * 32 + quad * 8];
#pragma unroll
    for (int i = 0; i < 4; i++)
#pragma unroll
      for (int j = 0; j < 4; j++)
        acc[i][j] = MFMA16(a[i], b[j], acc[i][j]);
  }
#pragma unroll
  for (int i = 0; i < 4; i++)
#pragma unroll
    for (int j = 0; j < 4; j++)
#pragma unroll
      for (int r = 0; r < 4; r++) {
        int mg = mBase + wm + i * 16 + quad * 4 + r;
        int ng = nBase + wn + j * 16 + lane15;
        int b_ = mg >> 11, s_ = mg & 2047, h_ = ng >> 6, d_ = ng & 63;
        Y[(((size_t)(b_ * 16 + h_)) * 2048 + s_) * 64 + d_] = (__bf16)(acc[i][j][r] * scale);
      }
}

// ---------------- output projection + fp32 residual (R3 2-barrier form) ----------------
__global__ __launch_bounds__(256) void gemm_wo(const __bf16* __restrict__ X,
    const __bf16* __restrict__ Wt, const float* __restrict__ resid,
    float* __restrict__ Yf) {
  __shared__ __align__(16) __bf16 As[128 * 32];
  __shared__ __align__(16) __bf16 Bs[128 * 32];
  const int t = threadIdx.x;
  const int lane = t & 63, w = t >> 6;
  const int lane15 = lane & 15, quad = lane >> 4;
  const int wm = (w >> 1) * 64, wn = (w & 1) * 64;
  const int mBase = blockIdx.y * 128, nBase = blockIdx.x * 128;
  const int c1 = t, c2 = t + 256;
  f32x4 acc[4][4] = {};
  for (int kt = 0; kt < 1024; kt += 32) {
    __syncthreads();
    g2l16(X  + (size_t)(mBase + (c1 >> 2)) * 1024 + kt + (c1 & 3) * 8, As + c1 * 8);
    g2l16(X  + (size_t)(mBase + (c2 >> 2)) * 1024 + kt + (c2 & 3) * 8, As + c2 * 8);
    g2l16(Wt + (size_t)(nBase + (c1 >> 2)) * 1024 + kt + (c1 & 3) * 8, Bs + c1 * 8);
    g2l16(Wt + (size_t)(nBase + (c2 >> 2)) * 1024 + kt + (c2 & 3) * 8, Bs + c2 * 8);
    __builtin_amdgcn_s_waitcnt(0);
    __syncthreads();
    bf16x8 a[4], b[4];
#pragma unroll
    for (int i = 0; i < 4; i++) a[i] = *(const bf16x8*)&As[(wm + i * 16 + lane15) * 32 + quad * 8];
#pragma unroll
    for (int j = 0; j < 4; j++) b[j] = *(const bf16x8*)&Bs[(wn + j * 16 + lane15) * 32 + quad * 8];
#pragma unroll
    for (int i = 0; i < 4; i++)
#pragma unroll
      for (int j = 0; j < 4; j++)
        acc[i][j] = MFMA16(a[i], b[j], acc[i][j]);
  }
#pragma unroll
  for (int i = 0; i < 4; i++)
#pragma unroll
    for (int j = 0; j < 4; j++)
#pragma unroll
      for (int r = 0; r < 4; r++) {
        int mg = mBase + wm + i * 16 + quad * 4 + r;
        int ng = nBase + wn + j * 16 + lane15;
        size_t idx = (size_t)mg * 1024 + ng;
        Yf[idx] = acc[i][j][r] + resid[idx];
      }
}

// ---------------- flash attention: 16x16 MFMA, S^T orientation, dbuf K/V ----------------
// Block: 4 waves x 16 q-rows; t-tiles of 64. S^T = K·Q^T puts q on C-cols ->
// one mask u64/lane/iter; t on C-rows -> reg pairs = consecutive t -> 8 packed
// b32 P-writes. LDS xor swizzle: element (row,e) at row*64 + ((e/8 ^ (row&7))*8) + e%8.
// K/V double-buffered: staging for kt+1 issued after the barrier, drained by the
// NEXT barrier's implicit vmcnt(0) -> staging latency hidden behind compute.
__global__ __launch_bounds__(256) void attn_kernel(const __bf16* __restrict__ Q,
    const __bf16* __restrict__ Kp, const __bf16* __restrict__ Vt,
    const unsigned long long* __restrict__ mbits, __bf16* __restrict__ ctx) {
  __shared__ __align__(16) __bf16 Ks[2][64 * 64];
  __shared__ __align__(16) __bf16 Vs[2][64 * 64];
  __shared__ __align__(16) __bf16 Ps[4][16 * 64];   // per-wave P; doubles as Q staging (64 rows)
  const int t = threadIdx.x, lane = t & 63, w = t >> 6;
  const int l15 = lane & 15, quad = lane >> 4, l7 = l15 & 7;
  const int bh = blockIdx.y, b = bh >> 4, h = bh & 15;
  const int qBase = blockIdx.x * 64;
  const size_t qko = (size_t)bh * 2048 * 64;
  const size_t vko = (size_t)bh * 64 * 2048;
  const int srow = lane >> 3, schunk = (lane & 7) ^ srow;   // staging map per 8-row group
  __bf16* Qs = &Ps[0][0];
  // stage Q rows 0..63 (wave w covers groups w and w+4)
  g2l16(Q + qko + (size_t)(qBase + w * 8 + srow) * 64 + schunk * 8,       Qs + w * 512 + lane * 8);
  g2l16(Q + qko + (size_t)(qBase + (w + 4) * 8 + srow) * 64 + schunk * 8, Qs + (w + 4) * 512 + lane * 8);
  // stage K/V tile 0 -> buffer 0
  g2l16(Kp + qko + (size_t)(w * 8 + srow) * 64 + schunk * 8,        &Ks[0][0] + w * 512 + lane * 8);
  g2l16(Kp + qko + (size_t)((w + 4) * 8 + srow) * 64 + schunk * 8,  &Ks[0][0] + (w + 4) * 512 + lane * 8);
  g2l16(Vt + vko + (size_t)(w * 8 + srow) * 2048 + schunk * 8,       &Vs[0][0] + w * 512 + lane * 8);
  g2l16(Vt + vko + (size_t)((w + 4) * 8 + srow) * 2048 + schunk * 8, &Vs[0][0] + (w + 4) * 512 + lane * 8);
  __builtin_amdgcn_s_waitcnt(0);
  __syncthreads();
  // Q fragments (B-operand [k=dk][n=q]); wave w reads only its own rows [w*16, w*16+16)
  bf16x8 qb0, qb1;
  {
    const int r = w * 16 + l15, s = r & 7;
    qb0 = *(const bf16x8*)&Qs[r * 64 + ((quad ^ s) * 8)];
    qb1 = *(const bf16x8*)&Qs[r * 64 + (((4 + quad) ^ s) * 8)];
  }
  bf16x8 ones;
#pragma unroll
  for (int i = 0; i < 8; i++) ones[i] = (__bf16)1.0f;
  f32x4 o[4] = {};
  f32x4 ol = {};
  const size_t mrow = ((size_t)b * 2048 + qBase + w * 16 + l15) * 32;
  unsigned long long w64 = mbits[mrow];
  int cur = 0;
  for (int kt = 0; kt < 32; ++kt) {
    __syncthreads();   // implicit vmcnt(0)+lgkm(0): tile kt staged; all reads of buf cur^1 done
    unsigned long long wnext = 0;
    if (kt < 31) {     // stage tile kt+1 into the buffer just released
      const int tB = (kt + 1) * 64, nb = cur ^ 1;
      g2l16(Kp + qko + (size_t)(tB + w * 8 + srow) * 64 + schunk * 8,        &Ks[nb][0] + w * 512 + lane * 8);
      g2l16(Kp + qko + (size_t)(tB + (w + 4) * 8 + srow) * 64 + schunk * 8,  &Ks[nb][0] + (w + 4) * 512 + lane * 8);
      g2l16(Vt + vko + (size_t)(w * 8 + srow) * 2048 + tB + schunk * 8,       &Vs[nb][0] + w * 512 + lane * 8);
      g2l16(Vt + vko + (size_t)((w + 4) * 8 + srow) * 2048 + tB + schunk * 8, &Vs[nb][0] + (w + 4) * 512 + lane * 8);
      wnext = mbits[mrow + kt + 1];
    }
    // S^T = K·Q^T: st[j] holds rows t = j*16+quad*4+r, col q = lane's q
    f32x4 st[4];
#pragma unroll
    for (int j = 0; j < 4; j++) {
      const int tr = j * 16 + l15, s = tr & 7;
      bf16x8 ka0 = *(const bf16x8*)&Ks[cur][tr * 64 + ((quad ^ s) * 8)];
      bf16x8 ka1 = *(const bf16x8*)&Ks[cur][tr * 64 + (((4 + quad) ^ s) * 8)];
      f32x4 z = {0.f, 0.f, 0.f, 0.f};
      z = MFMA16(ka0, qb0, z);
      st[j] = MFMA16(ka1, qb1, z);
    }
    // p = exp2(s) (Q pre-scaled by log2e/8), masked -> 0; packed b32 P-writes
#pragma unroll
    for (int j = 0; j < 4; j++) {
      const int t0 = j * 16 + quad * 4;
      float e0 = ((w64 >> (t0 + 0)) & 1ull) ? 0.f : __builtin_exp2f(st[j][0]);
      float e1 = ((w64 >> (t0 + 1)) & 1ull) ? 0.f : __builtin_exp2f(st[j][1]);
      float e2 = ((w64 >> (t0 + 2)) & 1ull) ? 0.f : __builtin_exp2f(st[j][2]);
      float e3 = ((w64 >> (t0 + 3)) & 1ull) ? 0.f : __builtin_exp2f(st[j][3]);
      const int ch = t0 >> 3;                         // = j*2 + (quad>>1)
      char* pbase = (char*)&Ps[w][0] + l15 * 128 + ((ch ^ l7) * 16) + ((t0 & 7) * 2);
      *(unsigned*)(pbase)     = pack_bf16(e0, e1);
      *(unsigned*)(pbase + 4) = pack_bf16(e2, e3);
    }
    w64 = wnext;
    __builtin_amdgcn_s_waitcnt(0xC07F);   // lgkmcnt(0): own-wave P writes visible
    bf16x8 pa0 = *(const bf16x8*)&Ps[w][l15 * 64 + ((quad ^ l7) * 8)];
    bf16x8 pa1 = *(const bf16x8*)&Ps[w][l15 * 64 + (((4 + quad) ^ l7) * 8)];
    ol = MFMA16(pa0, ones, ol);
    ol = MFMA16(pa1, ones, ol);
#pragma unroll
    for (int j = 0; j < 4; j++) {
      const int dr = j * 16 + l15, s2 = dr & 7;
      bf16x8 vb0 = *(const bf16x8*)&Vs[cur][dr * 64 + ((quad ^ s2) * 8)];
      bf16x8 vb1 = *(const bf16x8*)&Vs[cur][dr * 64 + (((4 + quad) ^ s2) * 8)];
      o[j] = MFMA16(pa0, vb0, o[j]);
      o[j] = MFMA16(pa1, vb1, o[j]);
    }
    cur ^= 1;
  }
  // epilogue: ctx[b][q][h*64 + j*16 + l15], q = qBase + w*16 + quad*4 + r
#pragma unroll
  for (int r = 0; r < 4; r++) {
    float inv = 1.f / ol[r];
    int qg = qBase + w * 16 + quad * 4 + r;
    size_t base = ((size_t)b * 2048 + qg) * 1024 + h * 64;
#pragma unroll
    for (int j = 0; j < 4; j++)
      ctx[base + j * 16 + l15] = (__bf16)(o[j][r] * inv);
  }
}

// ---------------- LayerNorm over D=1024 per row (fp32) ----------------
__global__ __launch_bounds__(256) void ln_kernel(const float* __restrict__ X,
    const float* __restrict__ gamma, const float* __restrict__ beta,
    float* __restrict__ out) {
  __shared__ float red[8];
  const int t = threadIdx.x;
  const size_t row = blockIdx.x;
  const float* xr = X + row * 1024;
  float4 x = *(const float4*)(xr + t * 4);
  float s = x.x + x.y + x.z + x.w;
  float s2 = x.x * x.x + x.y * x.y + x.z * x.z + x.w * x.w;
#pragma unroll
  for (int off = 1; off < 64; off <<= 1) { s += __shfl_xor(s, off); s2 += __shfl_xor(s2, off); }
  if ((t & 63) == 0) { red[t >> 6] = s; red[4 + (t >> 6)] = s2; }
  __syncthreads();
  float S1 = red[0] + red[1] + red[2] + red[3];
  float S2 = red[4] + red[5] + red[6] + red[7];
  float mu = S1 * (1.f / 1024.f);
  float var = S2 * (1.f / 1024.f) - mu * mu;
  float rs = rsqrtf(var + 1e-5f);
  float4 g = *(const float4*)(gamma + t * 4);
  float4 bb = *(const float4*)(beta + t * 4);
  float4 y;
  y.x = (x.x - mu) * rs * g.x + bb.x;
  y.y = (x.y - mu) * rs * g.y + bb.y;
  y.z = (x.z - mu) * rs * g.z + bb.z;
  y.w = (x.w - mu) * rs * g.w + bb.w;
  *(float4*)(out + row * 1024 + t * 4) = y;
}

extern "C" void kernel_launch(void* const* d_in, const int* in_sizes, int n_in,
                              void* d_out, int out_size, void* d_ws, size_t ws_size,
                              hipStream_t stream) {
  const float* inQ  = (const float*)d_in[0];
  const float* inK  = (const float*)d_in[1];
  const float* inV  = (const float*)d_in[2];
  const int*   mask = (const int*)d_in[3];
  const float* WQ   = (const float*)d_in[4];
  const float* WK   = (const float*)d_in[5];
  const float* WV   = (const float*)d_in[6];
  const float* WO   = (const float*)d_in[7];
  const float* gamma = (const float*)d_in[8];
  const float* beta  = (const float*)d_in[9];

  const size_t MB = 1024 * 1024;
  char* ws = (char*)d_ws;
  __bf16* Xq  = (__bf16*)(ws);                    // 8 MB each
  __bf16* Xk  = (__bf16*)(ws + 8 * MB);
  __bf16* Xv  = (__bf16*)(ws + 16 * MB);
  __bf16* Qb  = (__bf16*)(ws + 24 * MB);          // [BH][S][DK]
  __bf16* Kb  = (__bf16*)(ws + 32 * MB);
  __bf16* Vb  = (__bf16*)(ws + 40 * MB);
  __bf16* Vtb = (__bf16*)(ws + 48 * MB);          // [BH][DK][S]
  __bf16* Wt  = (__bf16*)(ws + 56 * MB);          // 4x 2MB bf16^T weights
  unsigned long long* mbits = (unsigned long long*)(ws + 64 * MB);
  __bf16* ctx  = Xq;                              // reuse
  float*  outp = (float*)(ws + 8 * MB);           // reuse Xk+Xv

  prep<<<dim3(11264), 256, 0, stream>>>(inQ, inK, inV, mask, WQ, WK, WV, WO,
                                        Xq, Xk, Xv, mbits, Wt);
  qkv_gemm<<<dim3(8, 32, 3), 256, 0, stream>>>(Xq, Xk, Xv, Wt, Qb, Kb, Vb);
  transpose_v<<<dim3(1, 32, 32), 256, 0, stream>>>(Vb, Vtb);
  attn_kernel<<<dim3(32, 32), 256, 0, stream>>>(Qb, Kb, Vtb, mbits, ctx);
  gemm_wo<<<dim3(8, 32), 256, 0, stream>>>(ctx, Wt + 3 * 1048576, inQ, outp);
  ln_kernel<<<dim3(4096), 256, 0, stream>>>(outp, gamma, beta, (float*)d_out);
}

// Round 6
// 317.108 us; speedup vs baseline: 1.2120x; 1.0169x over previous
//
#include <hip/hip_runtime.h>

// B=2, S=2048, D=1024, H=16, DK=64.  I/O fp32; internal MFMA pipeline bf16.
typedef __bf16 bf16x8 __attribute__((ext_vector_type(8)));
typedef float  f32x4  __attribute__((ext_vector_type(4)));

#define AS1 __attribute__((address_space(1)))
#define AS3 __attribute__((address_space(3)))

__device__ __forceinline__ void g2l16(const void* g, void* l) {
  __builtin_amdgcn_global_load_lds((AS1 void*)g, (AS3 void*)l, 16, 0, 0);
}
#define MFMA16(a, b, c) __builtin_amdgcn_mfma_f32_16x16x32_bf16(a, b, c, 0, 0, 0)

__device__ __forceinline__ unsigned pack_bf16(float a, float b) {
  union { __bf16 h[2]; unsigned u; } p;
  p.h[0] = (__bf16)a; p.h[1] = (__bf16)b;
  return p.u;
}

// ---------------- fused prep: cvt x3 | mask_pack | transpose_w4 ----------------
__global__ __launch_bounds__(256) void prep(const float* __restrict__ inQ,
    const float* __restrict__ inK, const float* __restrict__ inV,
    const int* __restrict__ mask,
    const float* __restrict__ W0, const float* __restrict__ W1,
    const float* __restrict__ W2, const float* __restrict__ W3,
    __bf16* __restrict__ Xq, __bf16* __restrict__ Xk, __bf16* __restrict__ Xv,
    unsigned long long* __restrict__ bits, __bf16* __restrict__ Wt) {
  __shared__ __bf16 tile[64][65];
  const int blk = blockIdx.x;
  if (blk < 6144) {
    const int z = blk >> 11, bx = blk & 2047;
    const float* src = z == 0 ? inQ : (z == 1 ? inK : inV);
    __bf16* dst = z == 0 ? Xq : (z == 1 ? Xk : Xv);
    size_t base = ((size_t)bx * 256 + threadIdx.x) * 8;
    float4 f0 = *(const float4*)(src + base);
    float4 f1 = *(const float4*)(src + base + 4);
    bf16x8 o;
    o[0] = (__bf16)f0.x; o[1] = (__bf16)f0.y; o[2] = (__bf16)f0.z; o[3] = (__bf16)f0.w;
    o[4] = (__bf16)f1.x; o[5] = (__bf16)f1.y; o[6] = (__bf16)f1.z; o[7] = (__bf16)f1.w;
    *(bf16x8*)(dst + base) = o;
  } else if (blk < 10240) {
    const int lane = threadIdx.x & 63, w = threadIdx.x >> 6;
    const int base = (blk - 6144) * 2048 + w * 512;
#pragma unroll
    for (int it = 0; it < 8; ++it) {
      int i = base + it * 64 + lane;
      unsigned long long bb = __ballot(mask[i] != 0);
      if (lane == 0) bits[i >> 6] = bb;
    }
  } else {
    const int idx = blk - 10240;
    const int z = idx >> 8, rem = idx & 255, bx = rem & 15, by = rem >> 4;
    const float* srcs[4] = {W0, W1, W2, W3};
    const float* src = srcs[z];
    __bf16* dst = Wt + (size_t)z * 1024 * 1024;
    int cb = bx * 64, rb = by * 64;
    for (int i = threadIdx.x; i < 4096; i += 256) {
      int r = i >> 6, c = i & 63;
      tile[r][c] = (__bf16)src[(size_t)(rb + r) * 1024 + cb + c];
    }
    __syncthreads();
    for (int i = threadIdx.x; i < 4096; i += 256) {
      int c = i >> 6, r = i & 63;
      dst[(size_t)(cb + c) * 1024 + rb + r] = tile[r][c];
    }
  }
}

// ---------------- QKV projection GEMM, 128x128 tile, BK=32 ----------------
// z=0: Q -> [BH][S][DK] scaled by log2e/8.  z=1: K -> [BH][S][DK].
// z=2: V -> V^T [BH][DK][S] directly (LDS restage epilogue; kills transpose_v).
__global__ __launch_bounds__(256) void qkv_gemm(const __bf16* __restrict__ Xq,
    const __bf16* __restrict__ Xk, const __bf16* __restrict__ Xv,
    const __bf16* __restrict__ Wt, __bf16* __restrict__ Qb,
    __bf16* __restrict__ Kb, __bf16* __restrict__ Vtb) {
  __shared__ __align__(16) __bf16 sh[8192];   // As | Bs; reused as 64x128 transpose buf
  __bf16* As = sh;
  __bf16* Bs = sh + 4096;
  const int z = blockIdx.z;
  const __bf16* X = z == 0 ? Xq : (z == 1 ? Xk : Xv);
  const __bf16* W = Wt + (size_t)z * 1048576;
  const float scale = z == 0 ? 0.125f * 1.44269504088896f : 1.f;
  const int t = threadIdx.x;
  const int lane = t & 63, w = t >> 6;
  const int lane15 = lane & 15, quad = lane >> 4;
  const int wm = (w >> 1) * 64, wn = (w & 1) * 64;
  const int mBase = blockIdx.y * 128, nBase = blockIdx.x * 128;
  const int c1 = t, c2 = t + 256;
  f32x4 acc[4][4] = {};
  for (int kt = 0; kt < 1024; kt += 32) {
    __syncthreads();
    g2l16(X + (size_t)(mBase + (c1 >> 2)) * 1024 + kt + (c1 & 3) * 8, As + c1 * 8);
    g2l16(X + (size_t)(mBase + (c2 >> 2)) * 1024 + kt + (c2 & 3) * 8, As + c2 * 8);
    g2l16(W + (size_t)(nBase + (c1 >> 2)) * 1024 + kt + (c1 & 3) * 8, Bs + c1 * 8);
    g2l16(W + (size_t)(nBase + (c2 >> 2)) * 1024 + kt + (c2 & 3) * 8, Bs + c2 * 8);
    __builtin_amdgcn_s_waitcnt(0);
    __syncthreads();
    bf16x8 a[4], b[4];
#pragma unroll
    for (int i = 0; i < 4; i++) a[i] = *(const bf16x8*)&As[(wm + i * 16 + lane15) * 32 + quad * 8];
#pragma unroll
    for (int j = 0; j < 4; j++) b[j] = *(const bf16x8*)&Bs[(wn + j * 16 + lane15) * 32 + quad * 8];
#pragma unroll
    for (int i = 0; i < 4; i++)
#pragma unroll
      for (int j = 0; j < 4; j++)
        acc[i][j] = MFMA16(a[i], b[j], acc[i][j]);
  }
  if (z != 2) {
    __bf16* Y = z == 0 ? Qb : Kb;
#pragma unroll
    for (int i = 0; i < 4; i++)
#pragma unroll
      for (int j = 0; j < 4; j++)
#pragma unroll
        for (int r = 0; r < 4; r++) {
          int mg = mBase + wm + i * 16 + quad * 4 + r;
          int ng = nBase + wn + j * 16 + lane15;
          int b_ = mg >> 11, s_ = mg & 2047, h_ = ng >> 6, d_ = ng & 63;
          Y[(((size_t)(b_ * 16 + h_)) * 2048 + s_) * 64 + d_] = (__bf16)(acc[i][j][r] * scale);
        }
  } else {
    // V^T epilogue: two 64-n halves through swizzled LDS (phys col = m ^ ((n&7)*16))
    const int s0 = mBase & 2047;
    const int bhBase = (mBase >> 11) * 16 + (nBase >> 6);
#pragma unroll
    for (int half = 0; half < 2; ++half) {
      __syncthreads();
      if ((w & 1) == half) {
#pragma unroll
        for (int i = 0; i < 4; i++)
#pragma unroll
          for (int j = 0; j < 4; j++)
#pragma unroll
            for (int r = 0; r < 4; r++) {
              int nl = j * 16 + lane15;
              int ml = wm + i * 16 + quad * 4 + r;
              sh[nl * 128 + (ml ^ ((nl & 7) * 16))] = (__bf16)acc[i][j][r];
            }
      }
      __syncthreads();
      const int row = t >> 2, c0 = (t & 3) * 32;
      const int xr = (row & 7) * 16;
      const int b0 = row * 128 + (c0 ^ xr);
      const int b1 = row * 128 + ((c0 + 16) ^ xr);
      bf16x8 a0 = *(const bf16x8*)&sh[b0];
      bf16x8 a1 = *(const bf16x8*)&sh[b0 + 8];
      bf16x8 a2 = *(const bf16x8*)&sh[b1];
      bf16x8 a3 = *(const bf16x8*)&sh[b1 + 8];
      __bf16* dst = Vtb + (size_t)(bhBase + half) * 131072 + (size_t)row * 2048 + s0 + c0;
      *(bf16x8*)(dst)      = a0;
      *(bf16x8*)(dst + 8)  = a1;
      *(bf16x8*)(dst + 16) = a2;
      *(bf16x8*)(dst + 24) = a3;
    }
  }
}

// ---------------- output projection + fp32 residual ----------------
__global__ __launch_bounds__(256) void gemm_wo(const __bf16* __restrict__ X,
    const __bf16* __restrict__ Wt, const float* __restrict__ resid,
    float* __restrict__ Yf) {
  __shared__ __align__(16) __bf16 As[128 * 32];
  __shared__ __align__(16) __bf16 Bs[128 * 32];
  const int t = threadIdx.x;
  const int lane = t & 63, w = t >> 6;
  const int lane15 = lane & 15, quad = lane >> 4;
  const int wm = (w >> 1) * 64, wn = (w & 1) * 64;
  const int mBase = blockIdx.y * 128, nBase = blockIdx.x * 128;
  const int c1 = t, c2 = t + 256;
  f32x4 acc[4][4] = {};
  for (int kt = 0; kt < 1024; kt += 32) {
    __syncthreads();
    g2l16(X  + (size_t)(mBase + (c1 >> 2)) * 1024 + kt + (c1 & 3) * 8, As + c1 * 8);
    g2l16(X  + (size_t)(mBase + (c2 >> 2)) * 1024 + kt + (c2 & 3) * 8, As + c2 * 8);
    g2l16(Wt + (size_t)(nBase + (c1 >> 2)) * 1024 + kt + (c1 & 3) * 8, Bs + c1 * 8);
    g2l16(Wt + (size_t)(nBase + (c2 >> 2)) * 1024 + kt + (c2 & 3) * 8, Bs + c2 * 8);
    __builtin_amdgcn_s_waitcnt(0);
    __syncthreads();
    bf16x8 a[4], b[4];
#pragma unroll
    for (int i = 0; i < 4; i++) a[i] = *(const bf16x8*)&As[(wm + i * 16 + lane15) * 32 + quad * 8];
#pragma unroll
    for (int j = 0; j < 4; j++) b[j] = *(const bf16x8*)&Bs[(wn + j * 16 + lane15) * 32 + quad * 8];
#pragma unroll
    for (int i = 0; i < 4; i++)
#pragma unroll
      for (int j = 0; j < 4; j++)
        acc[i][j] = MFMA16(a[i], b[j], acc[i][j]);
  }
#pragma unroll
  for (int i = 0; i < 4; i++)
#pragma unroll
    for (int j = 0; j < 4; j++)
#pragma unroll
      for (int r = 0; r < 4; r++) {
        int mg = mBase + wm + i * 16 + quad * 4 + r;
        int ng = nBase + wn + j * 16 + lane15;
        size_t idx = (size_t)mg * 1024 + ng;
        Yf[idx] = acc[i][j][r] + resid[idx];
      }
}

// ---------------- flash attention: 16x16 MFMA, t-tile 32, 28KB LDS ----------------
// Block: 4 waves x 16 q-rows (64 q); 64 t-tiles of 32, K/V double-buffered,
// single barrier per iter. S^T = K·Q^T (q on C-cols: 1 mask u32/lane/iter).
// Swizzles: 64-col rows -> chunk ^ (row&7); 32-col rows -> chunk ^ (row&3).
__global__ __launch_bounds__(256) void attn_kernel(const __bf16* __restrict__ Q,
    const __bf16* __restrict__ Kp, const __bf16* __restrict__ Vt,
    const unsigned* __restrict__ mbits, __bf16* __restrict__ ctx) {
  __shared__ __align__(16) __bf16 Qs[64 * 64];      // 8KB [q][dk]
  __shared__ __align__(16) __bf16 Ks[2][32 * 64];   // 8KB [t][dk]
  __shared__ __align__(16) __bf16 Vs[2][64 * 32];   // 8KB [d][t]
  __shared__ __align__(16) __bf16 Ps[4][16 * 32];   // 4KB per-wave [q][t]
  const int t = threadIdx.x, lane = t & 63, w = t >> 6;
  const int l15 = lane & 15, quad = lane >> 4;
  const int bh = blockIdx.y, b = bh >> 4, h = bh & 15;
  const int qBase = blockIdx.x * 64;
  const size_t qko = (size_t)bh * 2048 * 64;
  const size_t vko = (size_t)bh * 64 * 2048;
  const int srow8 = lane >> 3, sch8 = (lane & 7) ^ srow8;          // 64-col staging
  const int srow16 = lane >> 2, sch4 = (lane & 3) ^ (srow16 & 3);  // 32-col staging
  // stage Q (groups w, w+4) + K/V tile 0
  g2l16(Q + qko + (size_t)(qBase + w * 8 + srow8) * 64 + sch8 * 8,       Qs + w * 512 + lane * 8);
  g2l16(Q + qko + (size_t)(qBase + (w + 4) * 8 + srow8) * 64 + sch8 * 8, Qs + (w + 4) * 512 + lane * 8);
  g2l16(Kp + qko + (size_t)(w * 8 + srow8) * 64 + sch8 * 8,   &Ks[0][0] + w * 512 + lane * 8);
  g2l16(Vt + vko + (size_t)(w * 16 + srow16) * 2048 + sch4 * 8, &Vs[0][0] + w * 512 + lane * 8);
  __builtin_amdgcn_s_waitcnt(0);
  __syncthreads();
  bf16x8 qb0, qb1;
  {
    const int r = w * 16 + l15, s = r & 7;
    qb0 = *(const bf16x8*)&Qs[r * 64 + ((quad ^ s) * 8)];
    qb1 = *(const bf16x8*)&Qs[r * 64 + (((4 + quad) ^ s) * 8)];
  }
  bf16x8 ones;
#pragma unroll
  for (int i = 0; i < 8; i++) ones[i] = (__bf16)1.0f;
  f32x4 o[4] = {};
  f32x4 ol = {};
  const size_t mIdx = ((size_t)b * 2048 + qBase + w * 16 + l15) * 64;
  unsigned m32 = mbits[mIdx];
  int cur = 0;
  for (int kt = 0; kt < 64; ++kt) {
    __syncthreads();   // implicit full drain: tile kt staged (issued last iter)
    unsigned mnext = 0;
    if (kt < 63) {
      const int tB = (kt + 1) * 32, nb = cur ^ 1;
      g2l16(Kp + qko + (size_t)(tB + w * 8 + srow8) * 64 + sch8 * 8,        &Ks[nb][0] + w * 512 + lane * 8);
      g2l16(Vt + vko + (size_t)(w * 16 + srow16) * 2048 + tB + sch4 * 8,    &Vs[nb][0] + w * 512 + lane * 8);
      mnext = mbits[mIdx + kt + 1];
    }
    // S^T = K·Q^T : st[j] rows t=j*16+quad*4+r, col q=l15
    f32x4 st[2];
#pragma unroll
    for (int j = 0; j < 2; j++) {
      const int tr = j * 16 + l15, s = tr & 7;
      bf16x8 ka0 = *(const bf16x8*)&Ks[cur][tr * 64 + ((quad ^ s) * 8)];
      bf16x8 ka1 = *(const bf16x8*)&Ks[cur][tr * 64 + (((4 + quad) ^ s) * 8)];
      f32x4 zz = {0.f, 0.f, 0.f, 0.f};
      zz = MFMA16(ka0, qb0, zz);
      st[j] = MFMA16(ka1, qb1, zz);
    }
    // p = exp2(s), masked -> 0; packed b32 writes into Ps (row q=l15, 32-col)
#pragma unroll
    for (int j = 0; j < 2; j++) {
      const int t0 = j * 16 + quad * 4;
      float e0 = ((m32 >> (t0 + 0)) & 1u) ? 0.f : __builtin_exp2f(st[j][0]);
      float e1 = ((m32 >> (t0 + 1)) & 1u) ? 0.f : __builtin_exp2f(st[j][1]);
      float e2 = ((m32 >> (t0 + 2)) & 1u) ? 0.f : __builtin_exp2f(st[j][2]);
      float e3 = ((m32 >> (t0 + 3)) & 1u) ? 0.f : __builtin_exp2f(st[j][3]);
      const int ch = t0 >> 3;                       // j*2 + (quad>>1)
      char* pbase = (char*)&Ps[w][0] + l15 * 64 + ((ch ^ (l15 & 3)) * 16) + ((t0 & 7) * 2);
      *(unsigned*)(pbase)     = pack_bf16(e0, e1);
      *(unsigned*)(pbase + 4) = pack_bf16(e2, e3);
    }
    m32 = mnext;
    __builtin_amdgcn_s_waitcnt(0xC07F);   // lgkmcnt(0): own-wave P writes visible
    bf16x8 pa = *(const bf16x8*)&Ps[w][l15 * 32 + ((quad ^ (l15 & 3)) * 8)];
    ol = MFMA16(pa, ones, ol);
#pragma unroll
    for (int j = 0; j < 4; j++) {
      const int dr = j * 16 + l15;
      bf16x8 vb = *(const bf16x8*)&Vs[cur][dr * 32 + ((quad ^ (dr & 3)) * 8)];
      o[j] = MFMA16(pa, vb, o[j]);
    }
    cur ^= 1;
  }
#pragma unroll
  for (int r = 0; r < 4; r++) {
    float inv = 1.f / ol[r];
    int qg = qBase + w * 16 + quad * 4 + r;
    size_t base = ((size_t)b * 2048 + qg) * 1024 + h * 64;
#pragma unroll
    for (int j = 0; j < 4; j++)
      ctx[base + j * 16 + l15] = (__bf16)(o[j][r] * inv);
  }
}

// ---------------- LayerNorm over D=1024 per row (fp32) ----------------
__global__ __launch_bounds__(256) void ln_kernel(const float* __restrict__ X,
    const float* __restrict__ gamma, const float* __restrict__ beta,
    float* __restrict__ out) {
  __shared__ float red[8];
  const int t = threadIdx.x;
  const size_t row = blockIdx.x;
  const float* xr = X + row * 1024;
  float4 x = *(const float4*)(xr + t * 4);
  float s = x.x + x.y + x.z + x.w;
  float s2 = x.x * x.x + x.y * x.y + x.z * x.z + x.w * x.w;
#pragma unroll
  for (int off = 1; off < 64; off <<= 1) { s += __shfl_xor(s, off); s2 += __shfl_xor(s2, off); }
  if ((t & 63) == 0) { red[t >> 6] = s; red[4 + (t >> 6)] = s2; }
  __syncthreads();
  float S1 = red[0] + red[1] + red[2] + red[3];
  float S2 = red[4] + red[5] + red[6] + red[7];
  float mu = S1 * (1.f / 1024.f);
  float var = S2 * (1.f / 1024.f) - mu * mu;
  float rs = rsqrtf(var + 1e-5f);
  float4 g = *(const float4*)(gamma + t * 4);
  float4 bb = *(const float4*)(beta + t * 4);
  float4 y;
  y.x = (x.x - mu) * rs * g.x + bb.x;
  y.y = (x.y - mu) * rs * g.y + bb.y;
  y.z = (x.z - mu) * rs * g.z + bb.z;
  y.w = (x.w - mu) * rs * g.w + bb.w;
  *(float4*)(out + row * 1024 + t * 4) = y;
}

extern "C" void kernel_launch(void* const* d_in, const int* in_sizes, int n_in,
                              void* d_out, int out_size, void* d_ws, size_t ws_size,
                              hipStream_t stream) {
  const float* inQ  = (const float*)d_in[0];
  const float* inK  = (const float*)d_in[1];
  const float* inV  = (const float*)d_in[2];
  const int*   mask = (const int*)d_in[3];
  const float* WQ   = (const float*)d_in[4];
  const float* WK   = (const float*)d_in[5];
  const float* WV   = (const float*)d_in[6];
  const float* WO   = (const float*)d_in[7];
  const float* gamma = (const float*)d_in[8];
  const float* beta  = (const float*)d_in[9];

  const size_t MB = 1024 * 1024;
  char* ws = (char*)d_ws;
  __bf16* Xq  = (__bf16*)(ws);                    // 8 MB each
  __bf16* Xk  = (__bf16*)(ws + 8 * MB);
  __bf16* Xv  = (__bf16*)(ws + 16 * MB);
  __bf16* Qb  = (__bf16*)(ws + 24 * MB);          // [BH][S][DK]
  __bf16* Kb  = (__bf16*)(ws + 32 * MB);
  __bf16* Vtb = (__bf16*)(ws + 48 * MB);          // [BH][DK][S]
  __bf16* Wt  = (__bf16*)(ws + 56 * MB);          // 4x 2MB bf16^T weights
  unsigned long long* mbits = (unsigned long long*)(ws + 64 * MB);
  __bf16* ctx  = Xq;                              // reuse
  float*  outp = (float*)(ws + 8 * MB);           // reuse Xk+Xv

  prep<<<dim3(11264), 256, 0, stream>>>(inQ, inK, inV, mask, WQ, WK, WV, WO,
                                        Xq, Xk, Xv, mbits, Wt);
  qkv_gemm<<<dim3(8, 32, 3), 256, 0, stream>>>(Xq, Xk, Xv, Wt, Qb, Kb, Vtb);
  attn_kernel<<<dim3(32, 32), 256, 0, stream>>>(Qb, Kb, Vtb, (const unsigned*)mbits, ctx);
  gemm_wo<<<dim3(8, 32), 256, 0, stream>>>(ctx, Wt + 3 * 1048576, inQ, outp);
  ln_kernel<<<dim3(4096), 256, 0, stream>>>(outp, gamma, beta, (float*)d_out);
}

// Round 7
// 316.258 us; speedup vs baseline: 1.2152x; 1.0027x over previous
//
#include <hip/hip_runtime.h>

// B=2, S=2048, D=1024, H=16, DK=64.  I/O fp32; internal MFMA pipeline bf16.
typedef __bf16 bf16x8 __attribute__((ext_vector_type(8)));
typedef float  f32x4  __attribute__((ext_vector_type(4)));

#define AS1 __attribute__((address_space(1)))
#define AS3 __attribute__((address_space(3)))

__device__ __forceinline__ void g2l16(const void* g, void* l) {
  __builtin_amdgcn_global_load_lds((AS1 void*)g, (AS3 void*)l, 16, 0, 0);
}
#define MFMA16(a, b, c) __builtin_amdgcn_mfma_f32_16x16x32_bf16(a, b, c, 0, 0, 0)

__device__ __forceinline__ unsigned pack_bf16(float a, float b) {
  union { __bf16 h[2]; unsigned u; } p;
  p.h[0] = (__bf16)a; p.h[1] = (__bf16)b;
  return p.u;
}

// ---------------- fused prep: cvt x3 | mask -> f32 additive | transpose_w4 ----------------
__global__ __launch_bounds__(256) void prep(const float* __restrict__ inQ,
    const float* __restrict__ inK, const float* __restrict__ inV,
    const int* __restrict__ mask,
    const float* __restrict__ W0, const float* __restrict__ W1,
    const float* __restrict__ W2, const float* __restrict__ W3,
    __bf16* __restrict__ Xq, __bf16* __restrict__ Xk, __bf16* __restrict__ Xv,
    float* __restrict__ Mf, __bf16* __restrict__ Wt) {
  __shared__ __bf16 tile[64][65];
  const int blk = blockIdx.x;
  if (blk < 6144) {
    const int z = blk >> 11, bx = blk & 2047;
    const float* src = z == 0 ? inQ : (z == 1 ? inK : inV);
    __bf16* dst = z == 0 ? Xq : (z == 1 ? Xk : Xv);
    size_t base = ((size_t)bx * 256 + threadIdx.x) * 8;
    float4 f0 = *(const float4*)(src + base);
    float4 f1 = *(const float4*)(src + base + 4);
    bf16x8 o;
    o[0] = (__bf16)f0.x; o[1] = (__bf16)f0.y; o[2] = (__bf16)f0.z; o[3] = (__bf16)f0.w;
    o[4] = (__bf16)f1.x; o[5] = (__bf16)f1.y; o[6] = (__bf16)f1.z; o[7] = (__bf16)f1.w;
    *(bf16x8*)(dst + base) = o;
  } else if (blk < 10240) {
    // mask int32 -> f32 additive {0, -1e9}
    size_t base = ((size_t)(blk - 6144) * 2048) + (size_t)threadIdx.x * 8;
    int4 m0 = *(const int4*)(mask + base);
    int4 m1 = *(const int4*)(mask + base + 4);
    float4 f0, f1;
    f0.x = m0.x ? -1e9f : 0.f; f0.y = m0.y ? -1e9f : 0.f;
    f0.z = m0.z ? -1e9f : 0.f; f0.w = m0.w ? -1e9f : 0.f;
    f1.x = m1.x ? -1e9f : 0.f; f1.y = m1.y ? -1e9f : 0.f;
    f1.z = m1.z ? -1e9f : 0.f; f1.w = m1.w ? -1e9f : 0.f;
    *(float4*)(Mf + base) = f0;
    *(float4*)(Mf + base + 4) = f1;
  } else {
    const int idx = blk - 10240;
    const int z = idx >> 8, rem = idx & 255, bx = rem & 15, by = rem >> 4;
    const float* srcs[4] = {W0, W1, W2, W3};
    const float* src = srcs[z];
    __bf16* dst = Wt + (size_t)z * 1024 * 1024;
    int cb = bx * 64, rb = by * 64;
    for (int i = threadIdx.x; i < 4096; i += 256) {
      int r = i >> 6, c = i & 63;
      tile[r][c] = (__bf16)src[(size_t)(rb + r) * 1024 + cb + c];
    }
    __syncthreads();
    for (int i = threadIdx.x; i < 4096; i += 256) {
      int c = i >> 6, r = i & 63;
      dst[(size_t)(cb + c) * 1024 + rb + r] = tile[r][c];
    }
  }
}

// ---------------- QKV projection GEMM, 128x128 tile, BK=32 ----------------
// z=0: Q scaled by log2e/8.  z=1: K.  z=2: V -> V^T [BH][DK][S] via LDS restage.
__global__ __launch_bounds__(256) void qkv_gemm(const __bf16* __restrict__ Xq,
    const __bf16* __restrict__ Xk, const __bf16* __restrict__ Xv,
    const __bf16* __restrict__ Wt, __bf16* __restrict__ Qb,
    __bf16* __restrict__ Kb, __bf16* __restrict__ Vtb) {
  __shared__ __align__(16) __bf16 sh[8192];   // As | Bs; reused as 64x128 transpose buf
  __bf16* As = sh;
  __bf16* Bs = sh + 4096;
  const int z = blockIdx.z;
  const __bf16* X = z == 0 ? Xq : (z == 1 ? Xk : Xv);
  const __bf16* W = Wt + (size_t)z * 1048576;
  const float scale = z == 0 ? 0.125f * 1.44269504088896f : 1.f;
  const int t = threadIdx.x;
  const int lane = t & 63, w = t >> 6;
  const int lane15 = lane & 15, quad = lane >> 4;
  const int wm = (w >> 1) * 64, wn = (w & 1) * 64;
  const int mBase = blockIdx.y * 128, nBase = blockIdx.x * 128;
  const int c1 = t, c2 = t + 256;
  f32x4 acc[4][4] = {};
  for (int kt = 0; kt < 1024; kt += 32) {
    __syncthreads();
    g2l16(X + (size_t)(mBase + (c1 >> 2)) * 1024 + kt + (c1 & 3) * 8, As + c1 * 8);
    g2l16(X + (size_t)(mBase + (c2 >> 2)) * 1024 + kt + (c2 & 3) * 8, As + c2 * 8);
    g2l16(W + (size_t)(nBase + (c1 >> 2)) * 1024 + kt + (c1 & 3) * 8, Bs + c1 * 8);
    g2l16(W + (size_t)(nBase + (c2 >> 2)) * 1024 + kt + (c2 & 3) * 8, Bs + c2 * 8);
    __builtin_amdgcn_s_waitcnt(0);
    __syncthreads();
    bf16x8 a[4], b[4];
#pragma unroll
    for (int i = 0; i < 4; i++) a[i] = *(const bf16x8*)&As[(wm + i * 16 + lane15) * 32 + quad * 8];
#pragma unroll
    for (int j = 0; j < 4; j++) b[j] = *(const bf16x8*)&Bs[(wn + j * 16 + lane15) * 32 + quad * 8];
#pragma unroll
    for (int i = 0; i < 4; i++)
#pragma unroll
      for (int j = 0; j < 4; j++)
        acc[i][j] = MFMA16(a[i], b[j], acc[i][j]);
  }
  if (z != 2) {
    __bf16* Y = z == 0 ? Qb : Kb;
#pragma unroll
    for (int i = 0; i < 4; i++)
#pragma unroll
      for (int j = 0; j < 4; j++)
#pragma unroll
        for (int r = 0; r < 4; r++) {
          int mg = mBase + wm + i * 16 + quad * 4 + r;
          int ng = nBase + wn + j * 16 + lane15;
          int b_ = mg >> 11, s_ = mg & 2047, h_ = ng >> 6, d_ = ng & 63;
          Y[(((size_t)(b_ * 16 + h_)) * 2048 + s_) * 64 + d_] = (__bf16)(acc[i][j][r] * scale);
        }
  } else {
    const int s0 = mBase & 2047;
    const int bhBase = (mBase >> 11) * 16 + (nBase >> 6);
#pragma unroll
    for (int half = 0; half < 2; ++half) {
      __syncthreads();
      if ((w & 1) == half) {
#pragma unroll
        for (int i = 0; i < 4; i++)
#pragma unroll
          for (int j = 0; j < 4; j++)
#pragma unroll
            for (int r = 0; r < 4; r++) {
              int nl = j * 16 + lane15;
              int ml = wm + i * 16 + quad * 4 + r;
              sh[nl * 128 + (ml ^ ((nl & 7) * 16))] = (__bf16)acc[i][j][r];
            }
      }
      __syncthreads();
      const int row = t >> 2, c0 = (t & 3) * 32;
      const int xr = (row & 7) * 16;
      const int b0 = row * 128 + (c0 ^ xr);
      const int b1 = row * 128 + ((c0 + 16) ^ xr);
      bf16x8 a0 = *(const bf16x8*)&sh[b0];
      bf16x8 a1 = *(const bf16x8*)&sh[b0 + 8];
      bf16x8 a2 = *(const bf16x8*)&sh[b1];
      bf16x8 a3 = *(const bf16x8*)&sh[b1 + 8];
      __bf16* dst = Vtb + (size_t)(bhBase + half) * 131072 + (size_t)row * 2048 + s0 + c0;
      *(bf16x8*)(dst)      = a0;
      *(bf16x8*)(dst + 8)  = a1;
      *(bf16x8*)(dst + 16) = a2;
      *(bf16x8*)(dst + 24) = a3;
    }
  }
}

// ---------------- output projection + fp32 residual, 64x128 tile (512 blocks) ----------------
__global__ __launch_bounds__(256) void gemm_wo(const __bf16* __restrict__ X,
    const __bf16* __restrict__ Wt, const float* __restrict__ resid,
    float* __restrict__ Yf) {
  __shared__ __align__(16) __bf16 As[64 * 32];
  __shared__ __align__(16) __bf16 Bs[128 * 32];
  const int t = threadIdx.x;
  const int lane = t & 63, w = t >> 6;
  const int lane15 = lane & 15, quad = lane >> 4;
  const int wm = (w >> 1) * 32, wn = (w & 1) * 64;
  const int mBase = blockIdx.y * 64, nBase = blockIdx.x * 128;
  f32x4 acc[2][4] = {};
  for (int kt = 0; kt < 1024; kt += 32) {
    __syncthreads();
    g2l16(X  + (size_t)(mBase + (t >> 2)) * 1024 + kt + (t & 3) * 8, As + t * 8);
    g2l16(Wt + (size_t)(nBase + (t >> 2)) * 1024 + kt + (t & 3) * 8, Bs + t * 8);
    g2l16(Wt + (size_t)(nBase + ((t + 256) >> 2)) * 1024 + kt + (t & 3) * 8, Bs + (t + 256) * 8);
    __builtin_amdgcn_s_waitcnt(0);
    __syncthreads();
    bf16x8 a[2], b[4];
#pragma unroll
    for (int i = 0; i < 2; i++) a[i] = *(const bf16x8*)&As[(wm + i * 16 + lane15) * 32 + quad * 8];
#pragma unroll
    for (int j = 0; j < 4; j++) b[j] = *(const bf16x8*)&Bs[(wn + j * 16 + lane15) * 32 + quad * 8];
#pragma unroll
    for (int i = 0; i < 2; i++)
#pragma unroll
      for (int j = 0; j < 4; j++)
        acc[i][j] = MFMA16(a[i], b[j], acc[i][j]);
  }
#pragma unroll
  for (int i = 0; i < 2; i++)
#pragma unroll
    for (int j = 0; j < 4; j++)
#pragma unroll
      for (int r = 0; r < 4; r++) {
        int mg = mBase + wm + i * 16 + quad * 4 + r;
        int ng = nBase + wn + j * 16 + lane15;
        size_t idx = (size_t)mg * 1024 + ng;
        Yf[idx] = acc[i][j][r] + resid[idx];
      }
}

// ---------------- flash attention: 16x16 MFMA, t-tile 32, f32 additive mask ----------------
// Swizzles: 64-col rows -> chunk ^ (row&7); 32-col rows -> chunk ^ ((row>>1)&3)
// (32-col rows span 16 dwords: parity gives {0,16}, (r>>1)&3 gives 4 chunk rotations
//  -> 8 distinct bank groups x 2 rows = conflict-free).
__global__ __launch_bounds__(256) void attn_kernel(const __bf16* __restrict__ Q,
    const __bf16* __restrict__ Kp, const __bf16* __restrict__ Vt,
    const float* __restrict__ Mf, __bf16* __restrict__ ctx) {
  __shared__ __align__(16) __bf16 Qs[64 * 64];      // 8KB [q][dk]
  __shared__ __align__(16) __bf16 Ks[2][32 * 64];   // 8KB [t][dk]
  __shared__ __align__(16) __bf16 Vs[2][64 * 32];   // 8KB [d][t]
  __shared__ __align__(16) __bf16 Ps[4][16 * 32];   // 4KB per-wave [q][t]
  const int t = threadIdx.x, lane = t & 63, w = t >> 6;
  const int l15 = lane & 15, quad = lane >> 4;
  const int bh = blockIdx.y, b = bh >> 4, h = bh & 15;
  const int qBase = blockIdx.x * 64;
  const size_t qko = (size_t)bh * 2048 * 64;
  const size_t vko = (size_t)bh * 64 * 2048;
  const int srow8 = lane >> 3, sch8 = (lane & 7) ^ srow8;          // 64-col staging
  const int srow16 = lane >> 2, sch4 = (lane & 3) ^ ((lane >> 3) & 3);  // 32-col staging
  const int psw = (l15 >> 1) & 3;                                  // 32-col row swizzle for q-rows
  g2l16(Q + qko + (size_t)(qBase + w * 8 + srow8) * 64 + sch8 * 8,       Qs + w * 512 + lane * 8);
  g2l16(Q + qko + (size_t)(qBase + (w + 4) * 8 + srow8) * 64 + sch8 * 8, Qs + (w + 4) * 512 + lane * 8);
  g2l16(Kp + qko + (size_t)(w * 8 + srow8) * 64 + sch8 * 8,     &Ks[0][0] + w * 512 + lane * 8);
  g2l16(Vt + vko + (size_t)(w * 16 + srow16) * 2048 + sch4 * 8, &Vs[0][0] + w * 512 + lane * 8);
  const float* Mrow = Mf + ((size_t)b * 2048 + qBase + w * 16 + l15) * 2048 + quad * 4;
  float4 mc0 = *(const float4*)(Mrow);
  float4 mc1 = *(const float4*)(Mrow + 16);
  __builtin_amdgcn_s_waitcnt(0);
  __syncthreads();
  bf16x8 qb0, qb1;
  {
    const int r = w * 16 + l15, s = r & 7;
    qb0 = *(const bf16x8*)&Qs[r * 64 + ((quad ^ s) * 8)];
    qb1 = *(const bf16x8*)&Qs[r * 64 + (((4 + quad) ^ s) * 8)];
  }
  bf16x8 ones;
#pragma unroll
  for (int i = 0; i < 8; i++) ones[i] = (__bf16)1.0f;
  f32x4 o[4] = {};
  f32x4 ol = {};
  int cur = 0;
  for (int kt = 0; kt < 64; ++kt) {
    __syncthreads();   // implicit full drain: tile kt staged (issued last iter)
    float4 mn0, mn1;
    if (kt < 63) {
      const int tB = (kt + 1) * 32, nb = cur ^ 1;
      g2l16(Kp + qko + (size_t)(tB + w * 8 + srow8) * 64 + sch8 * 8,     &Ks[nb][0] + w * 512 + lane * 8);
      g2l16(Vt + vko + (size_t)(w * 16 + srow16) * 2048 + tB + sch4 * 8, &Vs[nb][0] + w * 512 + lane * 8);
      mn0 = *(const float4*)(Mrow + tB);
      mn1 = *(const float4*)(Mrow + tB + 16);
    }
    // S^T = K·Q^T : st[j] rows t=j*16+quad*4+r, col q=l15
    f32x4 st[2];
#pragma unroll
    for (int j = 0; j < 2; j++) {
      const int tr = j * 16 + l15, s = tr & 7;
      bf16x8 ka0 = *(const bf16x8*)&Ks[cur][tr * 64 + ((quad ^ s) * 8)];
      bf16x8 ka1 = *(const bf16x8*)&Ks[cur][tr * 64 + (((4 + quad) ^ s) * 8)];
      f32x4 zz = {0.f, 0.f, 0.f, 0.f};
      zz = MFMA16(ka0, qb0, zz);
      st[j] = MFMA16(ka1, qb1, zz);
    }
    // p = exp2(s + m): masked -> exp2(-1e9) = 0 exactly
#pragma unroll
    for (int j = 0; j < 2; j++) {
      const float4 mv = j == 0 ? mc0 : mc1;
      float e0 = __builtin_exp2f(st[j][0] + mv.x);
      float e1 = __builtin_exp2f(st[j][1] + mv.y);
      float e2 = __builtin_exp2f(st[j][2] + mv.z);
      float e3 = __builtin_exp2f(st[j][3] + mv.w);
      const int t0 = j * 16 + quad * 4;
      const int ch = t0 >> 3;
      char* pbase = (char*)&Ps[w][0] + l15 * 64 + ((ch ^ psw) * 16) + ((t0 & 7) * 2);
      *(unsigned*)(pbase)     = pack_bf16(e0, e1);
      *(unsigned*)(pbase + 4) = pack_bf16(e2, e3);
    }
    mc0 = mn0; mc1 = mn1;
    __builtin_amdgcn_s_waitcnt(0xC07F);   // lgkmcnt(0): own-wave P writes visible
    bf16x8 pa = *(const bf16x8*)&Ps[w][l15 * 32 + ((quad ^ psw) * 8)];
    ol = MFMA16(pa, ones, ol);
#pragma unroll
    for (int j = 0; j < 4; j++) {
      const int dr = j * 16 + l15;
      bf16x8 vb = *(const bf16x8*)&Vs[cur][dr * 32 + ((quad ^ ((dr >> 1) & 3)) * 8)];
      o[j] = MFMA16(pa, vb, o[j]);
    }
    cur ^= 1;
  }
#pragma unroll
  for (int r = 0; r < 4; r++) {
    float inv = 1.f / ol[r];
    int qg = qBase + w * 16 + quad * 4 + r;
    size_t base = ((size_t)b * 2048 + qg) * 1024 + h * 64;
#pragma unroll
    for (int j = 0; j < 4; j++)
      ctx[base + j * 16 + l15] = (__bf16)(o[j][r] * inv);
  }
}

// ---------------- LayerNorm over D=1024 per row (fp32) ----------------
__global__ __launch_bounds__(256) void ln_kernel(const float* __restrict__ X,
    const float* __restrict__ gamma, const float* __restrict__ beta,
    float* __restrict__ out) {
  __shared__ float red[8];
  const int t = threadIdx.x;
  const size_t row = blockIdx.x;
  const float* xr = X + row * 1024;
  float4 x = *(const float4*)(xr + t * 4);
  float s = x.x + x.y + x.z + x.w;
  float s2 = x.x * x.x + x.y * x.y + x.z * x.z + x.w * x.w;
#pragma unroll
  for (int off = 1; off < 64; off <<= 1) { s += __shfl_xor(s, off); s2 += __shfl_xor(s2, off); }
  if ((t & 63) == 0) { red[t >> 6] = s; red[4 + (t >> 6)] = s2; }
  __syncthreads();
  float S1 = red[0] + red[1] + red[2] + red[3];
  float S2 = red[4] + red[5] + red[6] + red[7];
  float mu = S1 * (1.f / 1024.f);
  float var = S2 * (1.f / 1024.f) - mu * mu;
  float rs = rsqrtf(var + 1e-5f);
  float4 g = *(const float4*)(gamma + t * 4);
  float4 bb = *(const float4*)(beta + t * 4);
  float4 y;
  y.x = (x.x - mu) * rs * g.x + bb.x;
  y.y = (x.y - mu) * rs * g.y + bb.y;
  y.z = (x.z - mu) * rs * g.z + bb.z;
  y.w = (x.w - mu) * rs * g.w + bb.w;
  *(float4*)(out + row * 1024 + t * 4) = y;
}

extern "C" void kernel_launch(void* const* d_in, const int* in_sizes, int n_in,
                              void* d_out, int out_size, void* d_ws, size_t ws_size,
                              hipStream_t stream) {
  const float* inQ  = (const float*)d_in[0];
  const float* inK  = (const float*)d_in[1];
  const float* inV  = (const float*)d_in[2];
  const int*   mask = (const int*)d_in[3];
  const float* WQ   = (const float*)d_in[4];
  const float* WK   = (const float*)d_in[5];
  const float* WV   = (const float*)d_in[6];
  const float* WO   = (const float*)d_in[7];
  const float* gamma = (const float*)d_in[8];
  const float* beta  = (const float*)d_in[9];

  const size_t MB = 1024 * 1024;
  char* ws = (char*)d_ws;
  __bf16* Xq  = (__bf16*)(ws);                    // 8 MB each
  __bf16* Xk  = (__bf16*)(ws + 8 * MB);
  __bf16* Xv  = (__bf16*)(ws + 16 * MB);
  __bf16* Qb  = (__bf16*)(ws + 24 * MB);          // [BH][S][DK]
  __bf16* Kb  = (__bf16*)(ws + 32 * MB);
  __bf16* Vtb = (__bf16*)(ws + 48 * MB);          // [BH][DK][S]
  __bf16* Wt  = (__bf16*)(ws + 56 * MB);          // 4x 2MB bf16^T weights
  float*  Mf  = (float*)(ws + 66 * MB);           // 32 MB additive f32 mask
  __bf16* ctx  = Xq;                              // reuse
  float*  outp = (float*)(ws + 8 * MB);           // reuse Xk+Xv

  prep<<<dim3(11264), 256, 0, stream>>>(inQ, inK, inV, mask, WQ, WK, WV, WO,
                                        Xq, Xk, Xv, Mf, Wt);
  qkv_gemm<<<dim3(8, 32, 3), 256, 0, stream>>>(Xq, Xk, Xv, Wt, Qb, Kb, Vtb);
  attn_kernel<<<dim3(32, 32), 256, 0, stream>>>(Qb, Kb, Vtb, Mf, ctx);
  gemm_wo<<<dim3(8, 64), 256, 0, stream>>>(ctx, Wt + 3 * 1048576, inQ, outp);
  ln_kernel<<<dim3(4096), 256, 0, stream>>>(outp, gamma, beta, (float*)d_out);
}

// Round 8
// 308.373 us; speedup vs baseline: 1.2463x; 1.0256x over previous
//
#include <hip/hip_runtime.h>

// B=2, S=2048, D=1024, H=16, DK=64.  I/O fp32; internal MFMA pipeline bf16.
typedef __bf16 bf16x8 __attribute__((ext_vector_type(8)));
typedef float  f32x4  __attribute__((ext_vector_type(4)));

#define AS1 __attribute__((address_space(1)))
#define AS3 __attribute__((address_space(3)))

__device__ __forceinline__ void g2l16(const void* g, void* l) {
  __builtin_amdgcn_global_load_lds((AS1 void*)g, (AS3 void*)l, 16, 0, 0);
}
#define MFMA16(a, b, c) __builtin_amdgcn_mfma_f32_16x16x32_bf16(a, b, c, 0, 0, 0)

__device__ __forceinline__ unsigned pack_bf16(float a, float b) {
  union { __bf16 h[2]; unsigned u; } p;
  p.h[0] = (__bf16)a; p.h[1] = (__bf16)b;
  return p.u;
}

// ---------------- fused prep: cvt x3 | mask -> bitmask | transpose_w4 ----------------
__global__ __launch_bounds__(256) void prep(const float* __restrict__ inQ,
    const float* __restrict__ inK, const float* __restrict__ inV,
    const int* __restrict__ mask,
    const float* __restrict__ W0, const float* __restrict__ W1,
    const float* __restrict__ W2, const float* __restrict__ W3,
    __bf16* __restrict__ Xq, __bf16* __restrict__ Xk, __bf16* __restrict__ Xv,
    unsigned long long* __restrict__ bits, __bf16* __restrict__ Wt) {
  __shared__ __bf16 tile[64][65];
  const int blk = blockIdx.x;
  if (blk < 6144) {
    const int z = blk >> 11, bx = blk & 2047;
    const float* src = z == 0 ? inQ : (z == 1 ? inK : inV);
    __bf16* dst = z == 0 ? Xq : (z == 1 ? Xk : Xv);
    size_t base = ((size_t)bx * 256 + threadIdx.x) * 8;
    float4 f0 = *(const float4*)(src + base);
    float4 f1 = *(const float4*)(src + base + 4);
    bf16x8 o;
    o[0] = (__bf16)f0.x; o[1] = (__bf16)f0.y; o[2] = (__bf16)f0.z; o[3] = (__bf16)f0.w;
    o[4] = (__bf16)f1.x; o[5] = (__bf16)f1.y; o[6] = (__bf16)f1.z; o[7] = (__bf16)f1.w;
    *(bf16x8*)(dst + base) = o;
  } else if (blk < 10240) {
    const int lane = threadIdx.x & 63, w = threadIdx.x >> 6;
    const int base = (blk - 6144) * 2048 + w * 512;
#pragma unroll
    for (int it = 0; it < 8; ++it) {
      int i = base + it * 64 + lane;
      unsigned long long bb = __ballot(mask[i] != 0);
      if (lane == 0) bits[i >> 6] = bb;
    }
  } else {
    const int idx = blk - 10240;
    const int z = idx >> 8, rem = idx & 255, bx = rem & 15, by = rem >> 4;
    const float* srcs[4] = {W0, W1, W2, W3};
    const float* src = srcs[z];
    __bf16* dst = Wt + (size_t)z * 1024 * 1024;
    int cb = bx * 64, rb = by * 64;
    for (int i = threadIdx.x; i < 4096; i += 256) {
      int r = i >> 6, c = i & 63;
      tile[r][c] = (__bf16)src[(size_t)(rb + r) * 1024 + cb + c];
    }
    __syncthreads();
    for (int i = threadIdx.x; i < 4096; i += 256) {
      int c = i >> 6, r = i & 63;
      dst[(size_t)(cb + c) * 1024 + rb + r] = tile[r][c];
    }
  }
}

// ---------------- QKV projection GEMM, 128x128 tile, BK=32 ----------------
// z=0: Q scaled by log2e/8.  z=1: K.  z=2: V -> V^T [BH][DK][S] via LDS restage.
__global__ __launch_bounds__(256) void qkv_gemm(const __bf16* __restrict__ Xq,
    const __bf16* __restrict__ Xk, const __bf16* __restrict__ Xv,
    const __bf16* __restrict__ Wt, __bf16* __restrict__ Qb,
    __bf16* __restrict__ Kb, __bf16* __restrict__ Vtb) {
  __shared__ __align__(16) __bf16 sh[8192];   // As | Bs; reused as 64x128 transpose buf
  __bf16* As = sh;
  __bf16* Bs = sh + 4096;
  const int z = blockIdx.z;
  const __bf16* X = z == 0 ? Xq : (z == 1 ? Xk : Xv);
  const __bf16* W = Wt + (size_t)z * 1048576;
  const float scale = z == 0 ? 0.125f * 1.44269504088896f : 1.f;
  const int t = threadIdx.x;
  const int lane = t & 63, w = t >> 6;
  const int lane15 = lane & 15, quad = lane >> 4;
  const int wm = (w >> 1) * 64, wn = (w & 1) * 64;
  const int mBase = blockIdx.y * 128, nBase = blockIdx.x * 128;
  const int c1 = t, c2 = t + 256;
  f32x4 acc[4][4] = {};
  for (int kt = 0; kt < 1024; kt += 32) {
    __syncthreads();
    g2l16(X + (size_t)(mBase + (c1 >> 2)) * 1024 + kt + (c1 & 3) * 8, As + c1 * 8);
    g2l16(X + (size_t)(mBase + (c2 >> 2)) * 1024 + kt + (c2 & 3) * 8, As + c2 * 8);
    g2l16(W + (size_t)(nBase + (c1 >> 2)) * 1024 + kt + (c1 & 3) * 8, Bs + c1 * 8);
    g2l16(W + (size_t)(nBase + (c2 >> 2)) * 1024 + kt + (c2 & 3) * 8, Bs + c2 * 8);
    __builtin_amdgcn_s_waitcnt(0);
    __syncthreads();
    bf16x8 a[4], b[4];
#pragma unroll
    for (int i = 0; i < 4; i++) a[i] = *(const bf16x8*)&As[(wm + i * 16 + lane15) * 32 + quad * 8];
#pragma unroll
    for (int j = 0; j < 4; j++) b[j] = *(const bf16x8*)&Bs[(wn + j * 16 + lane15) * 32 + quad * 8];
#pragma unroll
    for (int i = 0; i < 4; i++)
#pragma unroll
      for (int j = 0; j < 4; j++)
        acc[i][j] = MFMA16(a[i], b[j], acc[i][j]);
  }
  if (z != 2) {
    __bf16* Y = z == 0 ? Qb : Kb;
#pragma unroll
    for (int i = 0; i < 4; i++)
#pragma unroll
      for (int j = 0; j < 4; j++)
#pragma unroll
        for (int r = 0; r < 4; r++) {
          int mg = mBase + wm + i * 16 + quad * 4 + r;
          int ng = nBase + wn + j * 16 + lane15;
          int b_ = mg >> 11, s_ = mg & 2047, h_ = ng >> 6, d_ = ng & 63;
          Y[(((size_t)(b_ * 16 + h_)) * 2048 + s_) * 64 + d_] = (__bf16)(acc[i][j][r] * scale);
        }
  } else {
    const int s0 = mBase & 2047;
    const int bhBase = (mBase >> 11) * 16 + (nBase >> 6);
#pragma unroll
    for (int half = 0; half < 2; ++half) {
      __syncthreads();
      if ((w & 1) == half) {
#pragma unroll
        for (int i = 0; i < 4; i++)
#pragma unroll
          for (int j = 0; j < 4; j++)
#pragma unroll
            for (int r = 0; r < 4; r++) {
              int nl = j * 16 + lane15;
              int ml = wm + i * 16 + quad * 4 + r;
              sh[nl * 128 + (ml ^ ((nl & 7) * 16))] = (__bf16)acc[i][j][r];
            }
      }
      __syncthreads();
      const int row = t >> 2, c0 = (t & 3) * 32;
      const int xr = (row & 7) * 16;
      const int b0 = row * 128 + (c0 ^ xr);
      const int b1 = row * 128 + ((c0 + 16) ^ xr);
      bf16x8 a0 = *(const bf16x8*)&sh[b0];
      bf16x8 a1 = *(const bf16x8*)&sh[b0 + 8];
      bf16x8 a2 = *(const bf16x8*)&sh[b1];
      bf16x8 a3 = *(const bf16x8*)&sh[b1 + 8];
      __bf16* dst = Vtb + (size_t)(bhBase + half) * 131072 + (size_t)row * 2048 + s0 + c0;
      *(bf16x8*)(dst)      = a0;
      *(bf16x8*)(dst + 8)  = a1;
      *(bf16x8*)(dst + 16) = a2;
      *(bf16x8*)(dst + 24) = a3;
    }
  }
}

// ---------------- output projection + fp32 residual, 64x128 tile ----------------
__global__ __launch_bounds__(256) void gemm_wo(const __bf16* __restrict__ X,
    const __bf16* __restrict__ Wt, const float* __restrict__ resid,
    float* __restrict__ Yf) {
  __shared__ __align__(16) __bf16 As[64 * 32];
  __shared__ __align__(16) __bf16 Bs[128 * 32];
  const int t = threadIdx.x;
  const int lane = t & 63, w = t >> 6;
  const int lane15 = lane & 15, quad = lane >> 4;
  const int wm = (w >> 1) * 32, wn = (w & 1) * 64;
  const int mBase = blockIdx.y * 64, nBase = blockIdx.x * 128;
  f32x4 acc[2][4] = {};
  for (int kt = 0; kt < 1024; kt += 32) {
    __syncthreads();
    g2l16(X  + (size_t)(mBase + (t >> 2)) * 1024 + kt + (t & 3) * 8, As + t * 8);
    g2l16(Wt + (size_t)(nBase + (t >> 2)) * 1024 + kt + (t & 3) * 8, Bs + t * 8);
    g2l16(Wt + (size_t)(nBase + ((t + 256) >> 2)) * 1024 + kt + (t & 3) * 8, Bs + (t + 256) * 8);
    __builtin_amdgcn_s_waitcnt(0);
    __syncthreads();
    bf16x8 a[2], b[4];
#pragma unroll
    for (int i = 0; i < 2; i++) a[i] = *(const bf16x8*)&As[(wm + i * 16 + lane15) * 32 + quad * 8];
#pragma unroll
    for (int j = 0; j < 4; j++) b[j] = *(const bf16x8*)&Bs[(wn + j * 16 + lane15) * 32 + quad * 8];
#pragma unroll
    for (int i = 0; i < 2; i++)
#pragma unroll
      for (int j = 0; j < 4; j++)
        acc[i][j] = MFMA16(a[i], b[j], acc[i][j]);
  }
#pragma unroll
  for (int i = 0; i < 2; i++)
#pragma unroll
    for (int j = 0; j < 4; j++)
#pragma unroll
      for (int r = 0; r < 4; r++) {
        int mg = mBase + wm + i * 16 + quad * 4 + r;
        int ng = nBase + wn + j * 16 + lane15;
        size_t idx = (size_t)mg * 1024 + ng;
        Yf[idx] = acc[i][j][r] + resid[idx];
      }
}

// ---------------- flash attention: 16x16, t-tile 32, P/V software-pipelined ----------------
// Per iter kt: QK(kt) -> PV(kt-1) (independent MFMAs fill the MFMA->exp2 gap) ->
// exp2+P-write(kt) -> P-read(kt) (consumed next iter). Ps per-wave double-buffered;
// Vs 4-deep (stage kt+1 while reading kt-1). LDS 40KB -> 4 blocks/CU.
// Swizzles: 64-col rows: chunk^(row&7); 32-col rows: chunk^((row>>1)&3).
__global__ __launch_bounds__(256) void attn_kernel(const __bf16* __restrict__ Q,
    const __bf16* __restrict__ Kp, const __bf16* __restrict__ Vt,
    const unsigned* __restrict__ mbits, __bf16* __restrict__ ctx) {
  __shared__ __align__(16) __bf16 Qs[64 * 64];        // 8KB [q][dk]
  __shared__ __align__(16) __bf16 Ks[2][32 * 64];     // 8KB [t][dk]
  __shared__ __align__(16) __bf16 Vs[4][64 * 32];     // 16KB [d][t]
  __shared__ __align__(16) __bf16 Ps[4][2][16 * 32];  // 8KB per-wave dbuf [q][t]
  const int t = threadIdx.x, lane = t & 63, w = t >> 6;
  const int l15 = lane & 15, quad = lane >> 4;
  const int psw = (l15 >> 1) & 3;
  const int bh = blockIdx.y, b = bh >> 4, h = bh & 15;
  const int qBase = blockIdx.x * 64;
  const size_t qko = (size_t)bh * 2048 * 64;
  const size_t vko = (size_t)bh * 64 * 2048;
  const int srow8 = lane >> 3, sch8 = (lane & 7) ^ srow8;
  const int srow16 = lane >> 2, sch4 = (lane & 3) ^ ((lane >> 3) & 3);
  g2l16(Q + qko + (size_t)(qBase + w * 8 + srow8) * 64 + sch8 * 8,       Qs + w * 512 + lane * 8);
  g2l16(Q + qko + (size_t)(qBase + (w + 4) * 8 + srow8) * 64 + sch8 * 8, Qs + (w + 4) * 512 + lane * 8);
  g2l16(Kp + qko + (size_t)(w * 8 + srow8) * 64 + sch8 * 8,     &Ks[0][0] + w * 512 + lane * 8);
  g2l16(Vt + vko + (size_t)(w * 16 + srow16) * 2048 + sch4 * 8, &Vs[0][0] + w * 512 + lane * 8);
  const size_t mIdx = ((size_t)b * 2048 + qBase + w * 16 + l15) * 64;
  unsigned m32 = mbits[mIdx];
  __builtin_amdgcn_s_waitcnt(0);
  __syncthreads();
  bf16x8 qb0, qb1;
  {
    const int r = w * 16 + l15, s = r & 7;
    qb0 = *(const bf16x8*)&Qs[r * 64 + ((quad ^ s) * 8)];
    qb1 = *(const bf16x8*)&Qs[r * 64 + (((4 + quad) ^ s) * 8)];
  }
  bf16x8 ones;
#pragma unroll
  for (int i = 0; i < 8; i++) ones[i] = (__bf16)1.0f;
  f32x4 o[4] = {};
  f32x4 ol = {};
  bf16x8 pa_prev;
#pragma unroll 4
  for (int kt = 0; kt < 64; ++kt) {
    __syncthreads();   // implicit vmcnt(0)+lgkm(0): staging of tile kt complete
    unsigned mnext = 0;
    if (kt < 63) {
      const int tB = (kt + 1) * 32;
      g2l16(Kp + qko + (size_t)(tB + w * 8 + srow8) * 64 + sch8 * 8,     &Ks[(kt + 1) & 1][0] + w * 512 + lane * 8);
      g2l16(Vt + vko + (size_t)(w * 16 + srow16) * 2048 + tB + sch4 * 8, &Vs[(kt + 1) & 3][0] + w * 512 + lane * 8);
      mnext = mbits[mIdx + kt + 1];
    }
    // S^T(kt) = K·Q^T
    f32x4 st[2];
#pragma unroll
    for (int j = 0; j < 2; j++) {
      const int tr = j * 16 + l15, s = tr & 7;
      bf16x8 ka0 = *(const bf16x8*)&Ks[kt & 1][tr * 64 + ((quad ^ s) * 8)];
      bf16x8 ka1 = *(const bf16x8*)&Ks[kt & 1][tr * 64 + (((4 + quad) ^ s) * 8)];
      f32x4 zz = {0.f, 0.f, 0.f, 0.f};
      zz = MFMA16(ka0, qb0, zz);
      st[j] = MFMA16(ka1, qb1, zz);
    }
    // PV(kt-1): independent of st -> fills the MFMA->exp2 latency gap
    if (kt > 0) {
      const __bf16* Vb = &Vs[(kt - 1) & 3][0];
      ol = MFMA16(pa_prev, ones, ol);
#pragma unroll
      for (int j = 0; j < 4; j++) {
        const int dr = j * 16 + l15;
        bf16x8 vb = *(const bf16x8*)&Vb[dr * 32 + ((quad ^ ((dr >> 1) & 3)) * 8)];
        o[j] = MFMA16(pa_prev, vb, o[j]);
      }
    }
    // p = exp2(s), masked -> 0; packed b32 writes into Ps[w][kt&1]
    __bf16* Pw = &Ps[w][kt & 1][0];
#pragma unroll
    for (int j = 0; j < 2; j++) {
      const int t0 = j * 16 + quad * 4;
      float e0 = ((m32 >> (t0 + 0)) & 1u) ? 0.f : __builtin_exp2f(st[j][0]);
      float e1 = ((m32 >> (t0 + 1)) & 1u) ? 0.f : __builtin_exp2f(st[j][1]);
      float e2 = ((m32 >> (t0 + 2)) & 1u) ? 0.f : __builtin_exp2f(st[j][2]);
      float e3 = ((m32 >> (t0 + 3)) & 1u) ? 0.f : __builtin_exp2f(st[j][3]);
      const int ch = t0 >> 3;
      char* pbase = (char*)Pw + l15 * 64 + ((ch ^ psw) * 16) + ((t0 & 7) * 2);
      *(unsigned*)(pbase)     = pack_bf16(e0, e1);
      *(unsigned*)(pbase + 4) = pack_bf16(e2, e3);
    }
    m32 = mnext;
    __builtin_amdgcn_s_waitcnt(0xC07F);   // lgkmcnt(0): own-wave P writes visible
    pa_prev = *(const bf16x8*)&Pw[l15 * 32 + ((quad ^ psw) * 8)];
  }
  // drain: PV(63)
  {
    const __bf16* Vb = &Vs[63 & 3][0];
    ol = MFMA16(pa_prev, ones, ol);
#pragma unroll
    for (int j = 0; j < 4; j++) {
      const int dr = j * 16 + l15;
      bf16x8 vb = *(const bf16x8*)&Vb[dr * 32 + ((quad ^ ((dr >> 1) & 3)) * 8)];
      o[j] = MFMA16(pa_prev, vb, o[j]);
    }
  }
#pragma unroll
  for (int r = 0; r < 4; r++) {
    float inv = 1.f / ol[r];
    int qg = qBase + w * 16 + quad * 4 + r;
    size_t base = ((size_t)b * 2048 + qg) * 1024 + h * 64;
#pragma unroll
    for (int j = 0; j < 4; j++)
      ctx[base + j * 16 + l15] = (__bf16)(o[j][r] * inv);
  }
}

// ---------------- LayerNorm over D=1024 per row (fp32) ----------------
__global__ __launch_bounds__(256) void ln_kernel(const float* __restrict__ X,
    const float* __restrict__ gamma, const float* __restrict__ beta,
    float* __restrict__ out) {
  __shared__ float red[8];
  const int t = threadIdx.x;
  const size_t row = blockIdx.x;
  const float* xr = X + row * 1024;
  float4 x = *(const float4*)(xr + t * 4);
  float s = x.x + x.y + x.z + x.w;
  float s2 = x.x * x.x + x.y * x.y + x.z * x.z + x.w * x.w;
#pragma unroll
  for (int off = 1; off < 64; off <<= 1) { s += __shfl_xor(s, off); s2 += __shfl_xor(s2, off); }
  if ((t & 63) == 0) { red[t >> 6] = s; red[4 + (t >> 6)] = s2; }
  __syncthreads();
  float S1 = red[0] + red[1] + red[2] + red[3];
  float S2 = red[4] + red[5] + red[6] + red[7];
  float mu = S1 * (1.f / 1024.f);
  float var = S2 * (1.f / 1024.f) - mu * mu;
  float rs = rsqrtf(var + 1e-5f);
  float4 g = *(const float4*)(gamma + t * 4);
  float4 bb = *(const float4*)(beta + t * 4);
  float4 y;
  y.x = (x.x - mu) * rs * g.x + bb.x;
  y.y = (x.y - mu) * rs * g.y + bb.y;
  y.z = (x.z - mu) * rs * g.z + bb.z;
  y.w = (x.w - mu) * rs * g.w + bb.w;
  *(float4*)(out + row * 1024 + t * 4) = y;
}

extern "C" void kernel_launch(void* const* d_in, const int* in_sizes, int n_in,
                              void* d_out, int out_size, void* d_ws, size_t ws_size,
                              hipStream_t stream) {
  const float* inQ  = (const float*)d_in[0];
  const float* inK  = (const float*)d_in[1];
  const float* inV  = (const float*)d_in[2];
  const int*   mask = (const int*)d_in[3];
  const float* WQ   = (const float*)d_in[4];
  const float* WK   = (const float*)d_in[5];
  const float* WV   = (const float*)d_in[6];
  const float* WO   = (const float*)d_in[7];
  const float* gamma = (const float*)d_in[8];
  const float* beta  = (const float*)d_in[9];

  const size_t MB = 1024 * 1024;
  char* ws = (char*)d_ws;
  __bf16* Xq  = (__bf16*)(ws);                    // 8 MB each
  __bf16* Xk  = (__bf16*)(ws + 8 * MB);
  __bf16* Xv  = (__bf16*)(ws + 16 * MB);
  __bf16* Qb  = (__bf16*)(ws + 24 * MB);          // [BH][S][DK]
  __bf16* Kb  = (__bf16*)(ws + 32 * MB);
  __bf16* Vtb = (__bf16*)(ws + 48 * MB);          // [BH][DK][S]
  __bf16* Wt  = (__bf16*)(ws + 56 * MB);          // 4x 2MB bf16^T weights
  unsigned long long* mbits = (unsigned long long*)(ws + 64 * MB);  // 1 MB
  __bf16* ctx  = Xq;                              // reuse
  float*  outp = (float*)(ws + 8 * MB);           // reuse Xk+Xv

  prep<<<dim3(11264), 256, 0, stream>>>(inQ, inK, inV, mask, WQ, WK, WV, WO,
                                        Xq, Xk, Xv, mbits, Wt);
  qkv_gemm<<<dim3(8, 32, 3), 256, 0, stream>>>(Xq, Xk, Xv, Wt, Qb, Kb, Vtb);
  attn_kernel<<<dim3(32, 32), 256, 0, stream>>>(Qb, Kb, Vtb, (const unsigned*)mbits, ctx);
  gemm_wo<<<dim3(8, 64), 256, 0, stream>>>(ctx, Wt + 3 * 1048576, inQ, outp);
  ln_kernel<<<dim3(4096), 256, 0, stream>>>(outp, gamma, beta, (float*)d_out);
}